// Round 19
// baseline (221.943 us; speedup 1.0000x reference)
//
#include <hip/hip_runtime.h>

#define BDIM 8
#define NDIM 1024
#define KNN 20

typedef unsigned short u16;
typedef float f32x4 __attribute__((ext_vector_type(4)));
typedef short short8 __attribute__((ext_vector_type(8)));
typedef unsigned short ushort8 __attribute__((ext_vector_type(8)));

__device__ inline u16 f2bf(float f) {
  unsigned u = __float_as_uint(f);
  unsigned r = (u + 0x7fffu + ((u >> 16) & 1u)) >> 16;
  return (u16)r;
}
__device__ inline float bf2f(u16 v) {
  return __uint_as_float(((unsigned)v) << 16);
}

// ---- merged: KNN + fused edge1 (blocks 0..1023) + weight prep (blocks 1024+) ----
__global__ __launch_bounds__(512) void knn_wcvt(
    const float* __restrict__ x, int* __restrict__ nn,
    const float* __restrict__ w1_3, const float* __restrict__ w2_3,
    const float* __restrict__ w1_2, const float* __restrict__ w2_2,
    const float* __restrict__ hn_w1, const float* __restrict__ f_w,
    const float* __restrict__ he_w1, const float* __restrict__ he_w2,
    const float* __restrict__ he_b1, const float* __restrict__ he_b2,
    const float* __restrict__ bn_w1, const float* __restrict__ bn_w2,
    const float* __restrict__ n2_w1, const float* __restrict__ n2_w2,
    u16* __restrict__ w1b3e, u16* __restrict__ wpq3, u16* __restrict__ w2b3,
    u16* __restrict__ w1b2e, u16* __restrict__ wpq2, u16* __restrict__ w2b2,
    float* __restrict__ w1p1, u16* __restrict__ fwb,
    u16* __restrict__ wn1b, u16* __restrict__ wn2b,
    u16* __restrict__ wn21b, u16* __restrict__ wn22b,
    u16* __restrict__ e1out, float* __restrict__ m1out,
    int* __restrict__ pooled) {
  const int tid = threadIdx.x;
  if (blockIdx.x >= BDIM * 128) {
    const int idx = (blockIdx.x - BDIM * 128) * 512 + tid;
    if (idx < 512 * 384) fwb[idx] = f2bf(f_w[idx]);
    if (idx < 96 * 128) {
      int oc = idx >> 7, c = idx & 127;
      w1b3e[idx] = f2bf(w1_3[oc * 384 + c]);
    }
    if (idx < 192 * 128) {
      int n = idx >> 7, c = idx & 127;
      wpq3[idx] = f2bf(n < 96 ? w1_3[n * 384 + 128 + c]
                              : w1_3[(n - 96) * 384 + 256 + c]);
    }
    if (idx < 192 * 96) w2b3[idx] = f2bf(w2_3[idx]);
    if (idx < 48 * 64) {
      int oc = idx >> 6, c = idx & 63;
      w1b2e[idx] = f2bf(w1_2[oc * 192 + c]);
    }
    if (idx < 96 * 64) {
      int n = idx >> 6, c = idx & 63;
      wpq2[idx] = f2bf(n < 48 ? w1_2[n * 192 + 64 + c]
                              : w1_2[(n - 48) * 192 + 128 + c]);
    }
    if (idx < 128 * 64) {
      int oc = idx >> 6, i = idx & 63;
      w2b2[idx] = (i < 48) ? f2bf(w2_2[oc * 48 + i]) : (u16)0;
    }
    if (idx < 32 * 68) {
      int oc = idx / 68, c = idx - oc * 68;
      w1p1[idx] = (c < 67) ? hn_w1[oc * 67 + c] : 0.0f;
    }
    if (idx < 96 * 320) wn1b[idx] = f2bf(bn_w1[idx]);   // b2n_w1 [96][320]
    if (idx < 192 * 96) wn2b[idx] = f2bf(bn_w2[idx]);   // b2n_w2 [192][96]
    if (idx < 48 * 192) wn21b[idx] = f2bf(n2_w1[idx]);  // b1n_w1 [48][192]
    if (idx < 128 * 64) {                               // b1n_w2 [128][48->64]
      int oc = idx >> 6, i = idx & 63;
      wn22b[idx] = (i < 48) ? f2bf(n2_w2[oc * 48 + i]) : (u16)0;
    }
    if (idx < BDIM * 512) pooled[idx] = 0;
    return;
  }
  {
#pragma clang fp contract(off)
    __shared__ float xs0[NDIM], xs1[NDIM], xs2[NDIM], sq[NDIM];
    __shared__ int nns_l[8 * KNN];
    __shared__ u16 Xe[160 * 40];
    __shared__ u16 QYe[160 * 40];
    const int lane = tid & 63;
    const int w = tid >> 6;  // wave 0..7
    const int q = lane >> 4;
    const int b = blockIdx.x >> 7;
    const int nbase = (blockIdx.x & 127) << 3;
    const int n = nbase + w;
    for (int i = tid; i < NDIM; i += 512) {
      float a0 = x[(b * 3 + 0) * NDIM + i];
      float a1 = x[(b * 3 + 1) * NDIM + i];
      float a2 = x[(b * 3 + 2) * NDIM + i];
      xs0[i] = a0; xs1[i] = a1; xs2[i] = a2;
      sq[i] = (a0 * a0 + a1 * a1) + a2 * a2;
    }
    __syncthreads();
    const float xn0 = xs0[n], xn1 = xs1[n], xn2 = xs2[n], sqn = sq[n];
    float dl[16];
#pragma unroll
    for (int t = 0; t < 16; ++t) {
      int m = t * 64 + lane;
      float dot = (xn0 * xs0[m] + xn1 * xs1[m]) + xn2 * xs2[m];
      dl[t] = (sqn - 2.0f * dot) + sq[m];
    }
    int* nnrow = &nn[(b * NDIM + n) * KNN];
    for (int r = 0; r < KNN; ++r) {
      float bd = dl[0];
      int bt = 0;
#pragma unroll
      for (int t = 1; t < 16; ++t) {
        if (dl[t] < bd) { bd = dl[t]; bt = t; }
      }
      int bi = bt * 64 + lane;
#pragma unroll
      for (int off = 1; off < 64; off <<= 1) {
        float pd = __shfl_xor(bd, off);
        int pi = __shfl_xor(bi, off);
        if (pd < bd || (pd == bd && pi < bi)) { bd = pd; bi = pi; }
      }
      if (lane == 0) {
        nnrow[r] = bi;
        nns_l[w * KNN + r] = bi;
      }
      if ((bi & 63) == lane) {
        int wt = bi >> 6;
#pragma unroll
        for (int t = 0; t < 16; ++t) {
          if (t == wt) dl[t] = 3.4e38f;
        }
      }
    }
    __syncthreads();
    // ---- fused edge1: build X = [xi | xi-xj | xi | xj | 0pad] from LDS cloud ----
    const size_t bn0g = (size_t)b * NDIM + nbase;
    for (int idx = tid; idx < 160 * 4; idx += 512) {
      int p = idx >> 2, kc = idx & 3;
      int k0 = kc * 8;
      ushort8 r;
      if (kc < 2) {
        int lp = p / KNN;
        int pn = nbase + lp;
        int j = nns_l[p];
#pragma unroll
        for (int t = 0; t < 8; ++t) {
          int c = k0 + t;
          float v = 0.0f;
          if (c < 3) v = (c == 0 ? xs0[pn] : (c == 1 ? xs1[pn] : xs2[pn]));
          else if (c < 6) {
            int cc = c - 3;
            float ai = (cc == 0 ? xs0[pn] : (cc == 1 ? xs1[pn] : xs2[pn]));
            float aj = (cc == 0 ? xs0[j] : (cc == 1 ? xs1[j] : xs2[j]));
            v = ai - aj;
          } else if (c < 9) {
            int cc = c - 6;
            v = (cc == 0 ? xs0[pn] : (cc == 1 ? xs1[pn] : xs2[pn]));
          } else if (c < 12) {
            int cc = c - 9;
            v = (cc == 0 ? xs0[j] : (cc == 1 ? xs1[j] : xs2[j]));
          }
          r[t] = f2bf(v);
        }
      } else {
#pragma unroll
        for (int t = 0; t < 8; ++t) r[t] = 0;
      }
      *(ushort8*)&Xe[p * 40 + k0] = r;
    }
    __syncthreads();
    // ---- conv1: [160x32] @ he_w1^T (inline bf16) -> relu -> QYe [160x32] ----
    for (int job = w; job < 20; job += 8) {
      int mt = job >> 1, nt = job & 1;
      int row = mt * 16 + (lane & 15);
      int ncol = nt * 16 + (lane & 15);
      int kb = q * 8;
      ushort8 bfr;
#pragma unroll
      for (int t = 0; t < 8; ++t) {
        int c = kb + t;
        bfr[t] = (c < 12) ? f2bf(he_w1[ncol * 12 + c]) : (u16)0;
      }
      short8 a = *(const short8*)&Xe[row * 40 + kb];
      short8 bb = *(short8*)&bfr;
      f32x4 acc = {0.f, 0.f, 0.f, 0.f};
      acc = __builtin_amdgcn_mfma_f32_16x16x32_bf16(a, bb, acc, 0, 0, 0);
      float bias = he_b1[ncol];
      int m0 = mt * 16 + q * 4;
#pragma unroll
      for (int r = 0; r < 4; ++r)
        QYe[(m0 + r) * 40 + ncol] = f2bf(fmaxf(acc[r] + bias, 0.0f));
    }
    __syncthreads();
    // ---- conv2: [160x32] @ he_w2^T -> relu -> e1 + m1 (one job per wave) ----
    {
      int nt = w & 3, half = w >> 2;
      int ncol = nt * 16 + (lane & 15);
      int kb = q * 8;
      ushort8 bfr;
      {
        const float* s = &he_w2[ncol * 32 + kb];
        float4 f0 = *(const float4*)s;
        float4 f1 = *(const float4*)(s + 4);
        bfr[0] = f2bf(f0.x); bfr[1] = f2bf(f0.y); bfr[2] = f2bf(f0.z); bfr[3] = f2bf(f0.w);
        bfr[4] = f2bf(f1.x); bfr[5] = f2bf(f1.y); bfr[6] = f2bf(f1.z); bfr[7] = f2bf(f1.w);
      }
      short8 bb = *(short8*)&bfr;
      float bias = he_b2[ncol];
      float s[4] = {0.f, 0.f, 0.f, 0.f};
#pragma unroll
      for (int mi = 0; mi < 5; ++mi) {
        int mt = half * 5 + mi;
        short8 a = *(const short8*)&QYe[(mt * 16 + (lane & 15)) * 40 + kb];
        f32x4 acc = {0.f, 0.f, 0.f, 0.f};
        acc = __builtin_amdgcn_mfma_f32_16x16x32_bf16(a, bb, acc, 0, 0, 0);
        int m0 = mt * 16 + q * 4;
        float part = 0.0f;
#pragma unroll
        for (int r = 0; r < 4; ++r) {
          float yv = fmaxf(acc[r] + bias, 0.0f);
          e1out[(bn0g * KNN + m0 + r) * 64 + ncol] = f2bf(yv);
          part += yv;
        }
        int ptA = (4 * mt) / 5 - half * 4;
        int ptB = (4 * mt + 3) / 5 - half * 4;
        int qb = 5 * ((4 * mt + 3) / 5) - 4 * mt;
#pragma unroll
        for (int p2 = 0; p2 < 4; ++p2) {
          if (p2 == ptA && ptA == ptB) s[p2] += part;
          else if (p2 == ptA) s[p2] += (q < qb) ? part : 0.0f;
          else if (p2 == ptB) s[p2] += (q < qb) ? 0.0f : part;
        }
      }
#pragma unroll
      for (int p2 = 0; p2 < 4; ++p2) {
        float sv = s[p2];
        sv += __shfl_xor(sv, 16);
        sv += __shfl_xor(sv, 32);
        if (lane < 16)
          m1out[(bn0g + half * 4 + p2) * 64 + nt * 16 + lane] = sv;
      }
    }
  }
}

// ---- MFMA edge MP (lean v9): QY buffer aliasing, 2 barriers ----
template <int PTS, int CE, int CMID, int COUT, bool WRITE_E>
__global__ __launch_bounds__(256) void edge_mfma(
    const u16* __restrict__ eprev, const int* __restrict__ nnb,
    const u16* __restrict__ w1b, const float* __restrict__ b1v,
    const u16* __restrict__ w2b, const float* __restrict__ b2v,
    const u16* __restrict__ pq, u16* __restrict__ eout,
    float* __restrict__ mout) {
  constexpr int K2 = (CMID + 31) & ~31;
  constexpr int NPQ = 2 * CMID;
  constexpr int MT = PTS * KNN;       // 80 edges
  constexpr int MTL = MT / 16;        // 5 M-tiles (exact)
  constexpr int XPB = CE + 8;
  constexpr int QYP = K2 + 8;
  __shared__ u16 Xs[MT * XPB];
  __shared__ u16 QY[MT * QYP];
  __shared__ float pld[PTS * CMID];
  const int tid = threadIdx.x;
  const int lane = tid & 63;
  const int wv = tid >> 6;
  const int q = lane >> 4;
  const int bn0 = blockIdx.x * PTS;
  const int b = bn0 >> 10;
  // ---- bulk staging ----
  {
    constexpr int KC = CE / 8;
    for (int ch = tid; ch < MT * KC; ch += 256) {
      int p = ch / KC, kc = ch - p * KC;
      int k0 = kc * 8;
      *(uint4*)&Xs[p * XPB + k0] =
          *(const uint4*)&eprev[((size_t)blockIdx.x * MT + p) * CE + k0];
    }
    constexpr int QC = CMID / 8;
    for (int i = tid; i < MT * QC; i += 256) {
      int p = i / QC, c8 = (i - p * QC) * 8;
      int j = nnb[(size_t)bn0 * KNN + p];
      *(uint4*)&QY[p * QYP + c8] =
          *(const uint4*)&pq[((size_t)(b << 10) + j) * NPQ + CMID + c8];
    }
    if constexpr (K2 != CMID) {
      constexpr int PC = (K2 - CMID) / 8;
      for (int i = tid; i < MT * PC; i += 256) {
        int p = i / PC, c8 = CMID + (i - p * PC) * 8;
        uint4 z = {0, 0, 0, 0};
        *(uint4*)&QY[p * QYP + c8] = z;
      }
    }
    for (int i = tid; i < PTS * CMID; i += 256) {
      int pt = i / CMID, c = i - pt * CMID;
      pld[i] = bf2f(pq[(size_t)(bn0 + pt) * NPQ + c]) + b1v[c];
    }
  }
  __syncthreads();
  // ---- conv1 ----
  {
    constexpr int NT1 = CMID / 16;
    constexpr int J1 = MTL * NT1;
    constexpr int KS1 = CE / 32;
    for (int job = wv; job < J1; job += 4) {
      int mt = job / NT1, nt = job - mt * NT1;
      int row = mt * 16 + (lane & 15);
      int ncol = nt * 16 + (lane & 15);
      int kb = q * 8;
      f32x4 acc = {0.f, 0.f, 0.f, 0.f};
      const u16* ap = &Xs[row * XPB + kb];
      const u16* bp = &w1b[(size_t)ncol * CE + kb];
#pragma unroll
      for (int ks = 0; ks < KS1; ++ks) {
        short8 a = *(const short8*)(ap + ks * 32);
        short8 bb = *(const short8*)(bp + ks * 32);
        acc = __builtin_amdgcn_mfma_f32_16x16x32_bf16(a, bb, acc, 0, 0, 0);
      }
      int m0 = mt * 16 + q * 4;
      int pt = m0 / KNN;
      float padd = pld[pt * CMID + ncol];
#pragma unroll
      for (int r = 0; r < 4; ++r) {
        int m = m0 + r;
        float qadd = bf2f(QY[m * QYP + ncol]);
        float yv = fmaxf(acc[r] + padd + qadd, 0.0f);
        QY[m * QYP + ncol] = f2bf(yv);
      }
    }
  }
  __syncthreads();
  // ---- conv2: fp32 m-sum, const-folded pt map ----
  {
    constexpr int NT2 = COUT / 16;
    constexpr int KS2 = K2 / 32;
    for (int nt = wv; nt < NT2; nt += 4) {
      int ncol = nt * 16 + (lane & 15);
      int kb = q * 8;
      short8 bfrag[KS2];
      const u16* bp = &w2b[(size_t)ncol * K2 + kb];
#pragma unroll
      for (int ks = 0; ks < KS2; ++ks)
        bfrag[ks] = *(const short8*)(bp + ks * 32);
      float bias = b2v[ncol];
      float s[PTS];
#pragma unroll
      for (int pt = 0; pt < PTS; ++pt) s[pt] = 0.0f;
#pragma unroll
      for (int mt = 0; mt < MTL; ++mt) {
        f32x4 acc = {0.f, 0.f, 0.f, 0.f};
        const u16* ap = &QY[(mt * 16 + (lane & 15)) * QYP + kb];
#pragma unroll
        for (int ks = 0; ks < KS2; ++ks) {
          short8 a = *(const short8*)(ap + ks * 32);
          acc = __builtin_amdgcn_mfma_f32_16x16x32_bf16(a, bfrag[ks], acc, 0, 0, 0);
        }
        int m0 = mt * 16 + q * 4;
        float part = 0.0f;
#pragma unroll
        for (int r = 0; r < 4; ++r) {
          float yv = fmaxf(acc[r] + bias, 0.0f);
          if (WRITE_E)
            eout[((size_t)blockIdx.x * MT + m0 + r) * COUT + ncol] = f2bf(yv);
          part += yv;
        }
        int ptA = (4 * mt) / 5;
        int ptB = (4 * mt + 3) / 5;
        int qb = 5 * ptB - 4 * mt;
#pragma unroll
        for (int pt2 = 0; pt2 < PTS; ++pt2) {
          if (pt2 == ptA && ptA == ptB) s[pt2] += part;
          else if (pt2 == ptA) s[pt2] += (q < qb) ? part : 0.0f;
          else if (pt2 == ptB) s[pt2] += (q < qb) ? 0.0f : part;
        }
      }
#pragma unroll
      for (int pt = 0; pt < PTS; ++pt) {
        float sv = s[pt];
        sv += __shfl_xor(sv, 16);
        sv += __shfl_xor(sv, 32);
        if (lane < 16)
          mout[(size_t)(bn0 + pt) * COUT + nt * 16 + lane] = sv;
      }
    }
  }
}

// ---- node1 conv: fp32 microtile GEMM + fused PQ MFMA phase ----
template <int TP, int CH, int CM, int CINP, int CMID, int COUT, int NPQ, bool FIRSTH>
__global__ __launch_bounds__(256) void node_conv(
    const float* __restrict__ h, const float* __restrict__ inputs,
    const float* __restrict__ mbuf, const float* __restrict__ w1p,
    const float* __restrict__ b1v, const float* __restrict__ w2,
    const float* __restrict__ b2v, float* __restrict__ hout,
    const u16* __restrict__ wpq, u16* __restrict__ pq) {
  constexpr int CIN = CH + CM;
  constexpr int XP = CINP + 4;
  constexpr int Y1P = CMID + 4;
  constexpr int PG = TP / 4;
  constexpr int HP = COUT + 8;
  __shared__ float Xs[TP * XP];
  __shared__ float Y1s[TP * Y1P];
  __shared__ u16 Hb[(NPQ > 0) ? TP * HP : 8];
  const int tid = threadIdx.x;
  const int bn0 = blockIdx.x * TP;
  if constexpr (FIRSTH) {
    for (int idx = tid; idx < TP * CIN; idx += 256) {
      int p = idx / CIN, c = idx - p * CIN;
      int bn = bn0 + p;
      int b = bn >> 10, n = bn & (NDIM - 1);
      Xs[p * XP + c] = (c < CH) ? inputs[(b * 3 + c) * NDIM + n]
                                : mbuf[(size_t)bn * CM + (c - CH)];
    }
    if constexpr (CINP > CIN) {
      constexpr int PAD = CINP - CIN;
      for (int idx = tid; idx < TP * PAD; idx += 256) {
        int p = idx / PAD, c = CIN + idx % PAD;
        Xs[p * XP + c] = 0.0f;
      }
    }
  } else {
    constexpr int C4 = CIN / 4;
    for (int idx = tid; idx < TP * C4; idx += 256) {
      int p = idx / C4, c = (idx - p * C4) * 4;
      int bn = bn0 + p;
      float4 v = (c < CH) ? *(const float4*)&h[(size_t)bn * CH + c]
                          : *(const float4*)&mbuf[(size_t)bn * CM + (c - CH)];
      *(float4*)&Xs[p * XP + c] = v;
    }
  }
  __syncthreads();
  {
    constexpr int NT1 = PG * (CMID / 4);
    for (int t = tid; t < NT1; t += 256) {
      int pg = t % PG, og = t / PG;
      float acc[4][4];
#pragma unroll
      for (int j = 0; j < 4; ++j) {
        float bj = b1v[og * 4 + j];
#pragma unroll
        for (int i = 0; i < 4; ++i) acc[i][j] = bj;
      }
      for (int cin = 0; cin < CINP; cin += 4) {
        float4 xr[4], wr[4];
#pragma unroll
        for (int i = 0; i < 4; ++i)
          xr[i] = *(const float4*)&Xs[(pg * 4 + i) * XP + cin];
#pragma unroll
        for (int j = 0; j < 4; ++j)
          wr[j] = *(const float4*)&w1p[(size_t)(og * 4 + j) * CINP + cin];
#pragma unroll
        for (int i = 0; i < 4; ++i)
#pragma unroll
          for (int j = 0; j < 4; ++j) {
            acc[i][j] += xr[i].x * wr[j].x;
            acc[i][j] += xr[i].y * wr[j].y;
            acc[i][j] += xr[i].z * wr[j].z;
            acc[i][j] += xr[i].w * wr[j].w;
          }
      }
#pragma unroll
      for (int i = 0; i < 4; ++i)
#pragma unroll
        for (int j = 0; j < 4; ++j)
          Y1s[(pg * 4 + i) * Y1P + og * 4 + j] = fmaxf(acc[i][j], 0.0f);
    }
  }
  __syncthreads();
  {
    constexpr int NT2 = PG * (COUT / 4);
    for (int t = tid; t < NT2; t += 256) {
      int pg = t % PG, og = t / PG;
      float acc[4][4];
#pragma unroll
      for (int j = 0; j < 4; ++j) {
        float bj = b2v[og * 4 + j];
#pragma unroll
        for (int i = 0; i < 4; ++i) acc[i][j] = bj;
      }
      for (int cin = 0; cin < CMID; cin += 4) {
        float4 xr[4], wr[4];
#pragma unroll
        for (int i = 0; i < 4; ++i)
          xr[i] = *(const float4*)&Y1s[(pg * 4 + i) * Y1P + cin];
#pragma unroll
        for (int j = 0; j < 4; ++j)
          wr[j] = *(const float4*)&w2[(size_t)(og * 4 + j) * CMID + cin];
#pragma unroll
        for (int i = 0; i < 4; ++i)
#pragma unroll
          for (int j = 0; j < 4; ++j) {
            acc[i][j] += xr[i].x * wr[j].x;
            acc[i][j] += xr[i].y * wr[j].y;
            acc[i][j] += xr[i].z * wr[j].z;
            acc[i][j] += xr[i].w * wr[j].w;
          }
      }
#pragma unroll
      for (int i = 0; i < 4; ++i) {
        int bn = bn0 + pg * 4 + i;
#pragma unroll
        for (int j = 0; j < 4; ++j) {
          float v = fmaxf(acc[i][j], 0.0f);
          hout[(size_t)bn * COUT + og * 4 + j] = v;
          if constexpr (NPQ > 0) Hb[(pg * 4 + i) * HP + og * 4 + j] = f2bf(v);
        }
      }
    }
  }
  if constexpr (NPQ > 0) {
    __syncthreads();
    const int lane = tid & 63;
    const int wv = tid >> 6;
    constexpr int NT = NPQ / 16;
    constexpr int JOBS = (TP / 16) * NT;
    constexpr int KS = COUT / 32;
    for (int job = wv; job < JOBS; job += 4) {
      int mt = job / NT, nt = job - mt * NT;
      int row = mt * 16 + (lane & 15);
      int ncol = nt * 16 + (lane & 15);
      int kb = (lane >> 4) * 8;
      f32x4 acc = {0.f, 0.f, 0.f, 0.f};
      const u16* ap = &Hb[row * HP + kb];
      const u16* bp = &wpq[(size_t)ncol * COUT + kb];
#pragma unroll
      for (int ks = 0; ks < KS; ++ks) {
        short8 a = *(const short8*)(ap + ks * 32);
        short8 bb = *(const short8*)(bp + ks * 32);
        acc = __builtin_amdgcn_mfma_f32_16x16x32_bf16(a, bb, acc, 0, 0, 0);
      }
      int m0 = mt * 16 + (lane >> 4) * 4;
#pragma unroll
      for (int r = 0; r < 4; ++r)
        pq[(size_t)(bn0 + m0 + r) * NPQ + ncol] = f2bf(acc[r]);
    }
  }
}

// ---- node2 conv via MFMA: [h1|m2]->48->128 (h2) + pq3 phase ----
__global__ __launch_bounds__(256) void node2_mfma(
    const float* __restrict__ h1, const float* __restrict__ m2,
    const u16* __restrict__ w1b, const float* __restrict__ b1v,
    const u16* __restrict__ w2b, const float* __restrict__ b2v,
    float* __restrict__ h2out, const u16* __restrict__ wpq,
    u16* __restrict__ pq) {
  constexpr int TP = 32, XP = 200, Y1P = 72, HP = 136;
  __shared__ u16 Xb[TP * XP];
  __shared__ u16 Y1[TP * Y1P];
  __shared__ u16 Hb[TP * HP];
  const int tid = threadIdx.x;
  const int lane = tid & 63;
  const int wv = tid >> 6;
  const int q = lane >> 4;
  const int bn0 = blockIdx.x * TP;
  for (int i = tid; i < TP * 24; i += 256) {
    int p = i / 24, kc = i - p * 24;
    int k0 = kc * 8;
    const float* src = (k0 < 64) ? &h1[(size_t)(bn0 + p) * 64 + k0]
                                 : &m2[(size_t)(bn0 + p) * 128 + (k0 - 64)];
    float4 f0 = *(const float4*)src;
    float4 f1 = *(const float4*)(src + 4);
    ushort8 r;
    r[0] = f2bf(f0.x); r[1] = f2bf(f0.y); r[2] = f2bf(f0.z); r[3] = f2bf(f0.w);
    r[4] = f2bf(f1.x); r[5] = f2bf(f1.y); r[6] = f2bf(f1.z); r[7] = f2bf(f1.w);
    *(ushort8*)&Xb[p * XP + k0] = r;
  }
  for (int i = tid; i < TP * 2; i += 256) {
    int p = i >> 1, c8 = 48 + (i & 1) * 8;
    ushort8 z = {0, 0, 0, 0, 0, 0, 0, 0};
    *(ushort8*)&Y1[p * Y1P + c8] = z;
  }
  __syncthreads();
  for (int job = wv; job < 6; job += 4) {
    int mt = job / 3, nt = job - mt * 3;
    int row = mt * 16 + (lane & 15);
    int ncol = nt * 16 + (lane & 15);
    int kb = q * 8;
    f32x4 acc = {0.f, 0.f, 0.f, 0.f};
    const u16* ap = &Xb[row * XP + kb];
    const u16* bp = &w1b[(size_t)ncol * 192 + kb];
#pragma unroll
    for (int ks = 0; ks < 6; ++ks) {
      short8 a = *(const short8*)(ap + ks * 32);
      short8 bb = *(const short8*)(bp + ks * 32);
      acc = __builtin_amdgcn_mfma_f32_16x16x32_bf16(a, bb, acc, 0, 0, 0);
    }
    float bias = b1v[ncol];
    int m0 = mt * 16 + q * 4;
#pragma unroll
    for (int r = 0; r < 4; ++r)
      Y1[(m0 + r) * Y1P + ncol] = f2bf(fmaxf(acc[r] + bias, 0.0f));
  }
  __syncthreads();
  for (int job = wv; job < 16; job += 4) {
    int mt = job / 8, nt = job - mt * 8;
    int row = mt * 16 + (lane & 15);
    int ncol = nt * 16 + (lane & 15);
    int kb = q * 8;
    f32x4 acc = {0.f, 0.f, 0.f, 0.f};
    const u16* ap = &Y1[row * Y1P + kb];
    const u16* bp = &w2b[(size_t)ncol * 64 + kb];
#pragma unroll
    for (int ks = 0; ks < 2; ++ks) {
      short8 a = *(const short8*)(ap + ks * 32);
      short8 bb = *(const short8*)(bp + ks * 32);
      acc = __builtin_amdgcn_mfma_f32_16x16x32_bf16(a, bb, acc, 0, 0, 0);
    }
    float bias = b2v[ncol];
    int m0 = mt * 16 + q * 4;
#pragma unroll
    for (int r = 0; r < 4; ++r) {
      float v = fmaxf(acc[r] + bias, 0.0f);
      h2out[(size_t)(bn0 + m0 + r) * 128 + ncol] = v;
      Hb[(m0 + r) * HP + ncol] = f2bf(v);
    }
  }
  __syncthreads();
  for (int job = wv; job < 24; job += 4) {
    int mt = job / 12, nt = job - mt * 12;
    int row = mt * 16 + (lane & 15);
    int ncol = nt * 16 + (lane & 15);
    int kb = q * 8;
    f32x4 acc = {0.f, 0.f, 0.f, 0.f};
    const u16* ap = &Hb[row * HP + kb];
    const u16* bp = &wpq[(size_t)ncol * 128 + kb];
#pragma unroll
    for (int ks = 0; ks < 4; ++ks) {
      short8 a = *(const short8*)(ap + ks * 32);
      short8 bb = *(const short8*)(bp + ks * 32);
      acc = __builtin_amdgcn_mfma_f32_16x16x32_bf16(a, bb, acc, 0, 0, 0);
    }
    int m0 = mt * 16 + q * 4;
#pragma unroll
    for (int r = 0; r < 4; ++r)
      pq[(size_t)(bn0 + m0 + r) * 192 + ncol] = f2bf(acc[r]);
  }
}

// ---- fuse_pool v2: fused node3 (h2,m3 -> h3 in LDS) + fusion conv + max pool ----
__global__ __launch_bounds__(256) void fuse_pool_mfma(
    const float* __restrict__ h1, const float* __restrict__ h2,
    const float* __restrict__ m3, const u16* __restrict__ wn1b,
    const float* __restrict__ bn1v, const u16* __restrict__ wn2b,
    const float* __restrict__ bn2v, const u16* __restrict__ fwb,
    const float* __restrict__ fb, int* __restrict__ pooled) {
  constexpr int TP = 32;
  constexpr int XNP = 328;
  constexpr int Y1NP = 104;
  constexpr int XPB = 392;
  __shared__ __align__(16) char smem[TP * XPB * 2];
  u16* Xs = (u16*)smem;
  u16* Xn = (u16*)smem;
  __shared__ u16 Y1n[TP * Y1NP];
  __shared__ int pmax[512];
  const int tid = threadIdx.x;
  const int lane = tid & 63;
  const int wv = tid >> 6;
  const int q = lane >> 4;
  const int bn0 = blockIdx.x * TP;
  const int b = bn0 >> 10;
  for (int i = tid; i < 512; i += 256) pmax[i] = 0;
  for (int i = tid; i < TP * 41; i += 256) {
    int p = i / 41, kc = i - p * 41;
    int k0 = kc * 8;
    ushort8 r;
    if (kc < 16) {
      const float* src = &h2[(size_t)(bn0 + p) * 128 + k0];
      float4 f0 = *(const float4*)src;
      float4 f1 = *(const float4*)(src + 4);
      r[0] = f2bf(f0.x); r[1] = f2bf(f0.y); r[2] = f2bf(f0.z); r[3] = f2bf(f0.w);
      r[4] = f2bf(f1.x); r[5] = f2bf(f1.y); r[6] = f2bf(f1.z); r[7] = f2bf(f1.w);
    } else if (kc < 40) {
      const float* src = &m3[(size_t)(bn0 + p) * 192 + (k0 - 128)];
      float4 f0 = *(const float4*)src;
      float4 f1 = *(const float4*)(src + 4);
      r[0] = f2bf(f0.x); r[1] = f2bf(f0.y); r[2] = f2bf(f0.z); r[3] = f2bf(f0.w);
      r[4] = f2bf(f1.x); r[5] = f2bf(f1.y); r[6] = f2bf(f1.z); r[7] = f2bf(f1.w);
    } else {
#pragma unroll
      for (int t = 0; t < 8; ++t) r[t] = 0;
    }
    *(ushort8*)&Xn[p * XNP + k0] = r;
  }
  __syncthreads();
  for (int job = wv; job < 12; job += 4) {
    int mt = job / 6, nt = job - mt * 6;
    int row = mt * 16 + (lane & 15);
    int ncol = nt * 16 + (lane & 15);
    int kb = q * 8;
    f32x4 acc = {0.f, 0.f, 0.f, 0.f};
    const u16* ap = &Xn[row * XNP + kb];
    const u16* bp = &wn1b[(size_t)ncol * 320 + kb];
#pragma unroll
    for (int ks = 0; ks < 10; ++ks) {
      short8 a = *(const short8*)(ap + ks * 32);
      short8 bb = *(const short8*)(bp + ks * 32);
      acc = __builtin_amdgcn_mfma_f32_16x16x32_bf16(a, bb, acc, 0, 0, 0);
    }
    float bias = bn1v[ncol];
    int m0 = mt * 16 + q * 4;
#pragma unroll
    for (int r = 0; r < 4; ++r)
      Y1n[(m0 + r) * Y1NP + ncol] = f2bf(fmaxf(acc[r] + bias, 0.0f));
  }
  __syncthreads();
  for (int i = tid; i < TP * 24; i += 256) {
    int p = i / 24, kc = i - p * 24;
    int k0 = kc * 8;
    const float* src = (k0 < 64) ? &h1[(size_t)(bn0 + p) * 64 + k0]
                                 : &h2[(size_t)(bn0 + p) * 128 + (k0 - 64)];
    float4 f0 = *(const float4*)src;
    float4 f1 = *(const float4*)(src + 4);
    ushort8 r;
    r[0] = f2bf(f0.x); r[1] = f2bf(f0.y); r[2] = f2bf(f0.z); r[3] = f2bf(f0.w);
    r[4] = f2bf(f1.x); r[5] = f2bf(f1.y); r[6] = f2bf(f1.z); r[7] = f2bf(f1.w);
    *(ushort8*)&Xs[p * XPB + k0] = r;
  }
  if (tid < TP) {
    ushort8 z = {0, 0, 0, 0, 0, 0, 0, 0};
    *(ushort8*)&Xs[tid * XPB + 384] = z;
  }
  for (int job = wv; job < 24; job += 4) {
    int mt = job / 12, nt = job - mt * 12;
    int row = mt * 16 + (lane & 15);
    int ncol = nt * 16 + (lane & 15);
    int kb = q * 8;
    f32x4 acc = {0.f, 0.f, 0.f, 0.f};
    const u16* ap = &Y1n[row * Y1NP + kb];
    const u16* bp = &wn2b[(size_t)ncol * 96 + kb];
#pragma unroll
    for (int ks = 0; ks < 3; ++ks) {
      short8 a = *(const short8*)(ap + ks * 32);
      short8 bb = *(const short8*)(bp + ks * 32);
      acc = __builtin_amdgcn_mfma_f32_16x16x32_bf16(a, bb, acc, 0, 0, 0);
    }
    float bias = bn2v[ncol];
    int m0 = mt * 16 + q * 4;
#pragma unroll
    for (int r = 0; r < 4; ++r)
      Xs[(m0 + r) * XPB + 192 + ncol] = f2bf(fmaxf(acc[r] + bias, 0.0f));
  }
  __syncthreads();
  for (int job = wv; job < 64; job += 4) {
    int mt = job / 32, nt = job - mt * 32;
    int row = mt * 16 + (lane & 15);
    int ncol = nt * 16 + (lane & 15);
    int kb = q * 8;
    f32x4 acc = {0.f, 0.f, 0.f, 0.f};
    const u16* ap = &Xs[row * XPB + kb];
    const u16* bp = &fwb[(size_t)ncol * 384 + kb];
#pragma unroll
    for (int ks = 0; ks < 12; ++ks) {
      short8 a = *(const short8*)(ap + ks * 32);
      short8 bb = *(const short8*)(bp + ks * 32);
      acc = __builtin_amdgcn_mfma_f32_16x16x32_bf16(a, bb, acc, 0, 0, 0);
    }
    float bias = fb[ncol];
    float v = fmaxf(fmaxf(acc[0], acc[1]), fmaxf(acc[2], acc[3]));
    v = fmaxf(v + bias, 0.0f);
    v = fmaxf(v, __shfl_xor(v, 16));
    v = fmaxf(v, __shfl_xor(v, 32));
    if (lane < 16) atomicMax(&pmax[ncol], __float_as_int(v));
  }
  __syncthreads();
  for (int i = tid; i < 512; i += 256)
    atomicMax(&pooled[b * 512 + i], pmax[i]);
}

// ---------------- prediction head (blocks 0..7) + inputs echo copy (blocks 8+) ----------------
__global__ __launch_bounds__(256) void head_kernel(
    const int* __restrict__ pooledi, const float* __restrict__ p1w,
    const float* __restrict__ p1b, const float* __restrict__ p2w,
    const float* __restrict__ p2b, const float* __restrict__ p3w,
    const float* __restrict__ p3b, const float* __restrict__ inputs,
    float* __restrict__ out) {
  const int tid = threadIdx.x;
  if (blockIdx.x >= BDIM) {
    int idx = (blockIdx.x - BDIM) * 256 + tid;
    if (idx < (BDIM * 3 * NDIM) / 4) {
      const float4* src = (const float4*)inputs;
      float4* dst = (float4*)(out + BDIM * 40);
      dst[idx] = src[idx];
    }
    return;
  }
  __shared__ float xs[512], y1[256], y2[128];
  const int b = blockIdx.x;
  for (int i = tid; i < 512; i += 256) xs[i] = __int_as_float(pooledi[b * 512 + i]);
  __syncthreads();
  {
    float acc = p1b[tid];
    for (int c = 0; c < 512; ++c) acc += xs[c] * p1w[tid * 512 + c];
    y1[tid] = fmaxf(acc, 0.0f);
  }
  __syncthreads();
  if (tid < 128) {
    float acc = p2b[tid];
    for (int c = 0; c < 256; ++c) acc += y1[c] * p2w[tid * 256 + c];
    y2[tid] = fmaxf(acc, 0.0f);
  }
  __syncthreads();
  if (tid < 40) {
    float acc = p3b[tid];
    for (int c = 0; c < 128; ++c) acc += y2[c] * p3w[tid * 128 + c];
    out[b * 40 + tid] = acc;
  }
}

extern "C" void kernel_launch(void* const* d_in, const int* in_sizes, int n_in,
                              void* d_out, int out_size, void* d_ws,
                              size_t ws_size, hipStream_t stream) {
  const float* inputs = (const float*)d_in[0];
  const float* he_w1 = (const float*)d_in[1];
  const float* he_b1 = (const float*)d_in[2];
  const float* he_w2 = (const float*)d_in[3];
  const float* he_b2 = (const float*)d_in[4];
  const float* hn_w1 = (const float*)d_in[5];
  const float* hn_b1 = (const float*)d_in[6];
  const float* hn_w2 = (const float*)d_in[7];
  const float* hn_b2 = (const float*)d_in[8];
  const float* b1e_w1 = (const float*)d_in[9];
  const float* b1e_b1 = (const float*)d_in[10];
  const float* b1e_w2 = (const float*)d_in[11];
  const float* b1e_b2 = (const float*)d_in[12];
  const float* b1n_w1 = (const float*)d_in[13];
  const float* b1n_b1 = (const float*)d_in[14];
  const float* b1n_w2 = (const float*)d_in[15];
  const float* b1n_b2 = (const float*)d_in[16];
  const float* b2e_w1 = (const float*)d_in[17];
  const float* b2e_b1 = (const float*)d_in[18];
  const float* b2e_w2 = (const float*)d_in[19];
  const float* b2e_b2 = (const float*)d_in[20];
  const float* b2n_w1 = (const float*)d_in[21];
  const float* b2n_b1 = (const float*)d_in[22];
  const float* b2n_w2 = (const float*)d_in[23];
  const float* b2n_b2 = (const float*)d_in[24];
  const float* f_w = (const float*)d_in[25];
  const float* f_b = (const float*)d_in[26];
  const float* p1_w = (const float*)d_in[27];
  const float* p1_b = (const float*)d_in[28];
  const float* p2_w = (const float*)d_in[29];
  const float* p2_b = (const float*)d_in[30];
  const float* p3_w = (const float*)d_in[31];
  const float* p3_b = (const float*)d_in[32];
  float* out = (float*)d_out;

  char* ws = (char*)d_ws;
  size_t off = 0;
  auto alloc = [&](size_t bytes) {
    void* p = ws + off;
    off += (bytes + 255) & ~(size_t)255;
    return p;
  };
  int* nn = (int*)alloc((size_t)BDIM * NDIM * KNN * 4);
  float* m1 = (float*)alloc((size_t)BDIM * NDIM * 64 * 4);
  float* h1 = (float*)alloc((size_t)BDIM * NDIM * 64 * 4);
  u16* e1 = (u16*)alloc((size_t)BDIM * NDIM * KNN * 64 * 2);   // bf16
  float* m2 = (float*)alloc((size_t)BDIM * NDIM * 128 * 4);
  float* h2 = (float*)alloc((size_t)BDIM * NDIM * 128 * 4);
  u16* e2 = (u16*)alloc((size_t)BDIM * NDIM * KNN * 128 * 2);  // bf16
  float* m3 = (float*)alloc((size_t)BDIM * NDIM * 192 * 4);
  u16* pq2 = (u16*)alloc((size_t)BDIM * NDIM * 96 * 2);        // bf16
  u16* pq3 = (u16*)alloc((size_t)BDIM * NDIM * 192 * 2);       // bf16
  int* pooled = (int*)alloc((size_t)BDIM * 512 * 4);
  u16* w1b3e = (u16*)alloc((size_t)96 * 128 * 2);
  u16* wpq3 = (u16*)alloc((size_t)192 * 128 * 2);
  u16* w2b3 = (u16*)alloc((size_t)192 * 96 * 2);
  u16* w1b2e = (u16*)alloc((size_t)48 * 64 * 2);
  u16* wpq2 = (u16*)alloc((size_t)96 * 64 * 2);
  u16* w2b2 = (u16*)alloc((size_t)128 * 64 * 2);
  float* w1p1 = (float*)alloc((size_t)32 * 68 * 4);
  u16* fwb = (u16*)alloc((size_t)512 * 384 * 2);
  u16* wn1b = (u16*)alloc((size_t)96 * 320 * 2);
  u16* wn2b = (u16*)alloc((size_t)192 * 96 * 2);
  u16* wn21b = (u16*)alloc((size_t)48 * 192 * 2);
  u16* wn22b = (u16*)alloc((size_t)128 * 64 * 2);

  knn_wcvt<<<BDIM * 128 + 384, 512, 0, stream>>>(
      inputs, nn, b2e_w1, b2e_w2, b1e_w1, b1e_w2, hn_w1, f_w, he_w1, he_w2,
      he_b1, he_b2, b2n_w1, b2n_w2, b1n_w1, b1n_w2, w1b3e, wpq3, w2b3, w1b2e,
      wpq2, w2b2, w1p1, fwb, wn1b, wn2b, wn21b, wn22b, e1, m1, pooled);

  node_conv<64, 3, 64, 68, 32, 64, 96, true><<<BDIM * NDIM / 64, 256, 0, stream>>>(
      nullptr, inputs, m1, w1p1, hn_b1, hn_w2, hn_b2, h1, wpq2, pq2);

  edge_mfma<4, 64, 48, 128, true><<<BDIM * NDIM / 4, 256, 0, stream>>>(
      e1, nn, w1b2e, b1e_b1, w2b2, b1e_b2, pq2, e2, m2);
  node2_mfma<<<BDIM * NDIM / 32, 256, 0, stream>>>(
      h1, m2, wn21b, b1n_b1, wn22b, b1n_b2, h2, wpq3, pq3);

  edge_mfma<4, 128, 96, 192, false><<<BDIM * NDIM / 4, 256, 0, stream>>>(
      e2, nn, w1b3e, b2e_b1, w2b3, b2e_b2, pq3, nullptr, m3);

  fuse_pool_mfma<<<BDIM * NDIM / 32, 256, 0, stream>>>(
      h1, h2, m3, wn1b, b2n_b1, wn2b, b2n_b2, fwb, f_b, pooled);
  head_kernel<<<BDIM + 24, 256, 0, stream>>>(pooled, p1_w, p1_b, p2_w, p2_b,
                                             p3_w, p3_b, inputs, out);
}

// Round 20
// 214.412 us; speedup vs baseline: 1.0351x; 1.0351x over previous
//
#include <hip/hip_runtime.h>

#define BDIM 8
#define NDIM 1024
#define KNN 20

typedef unsigned short u16;
typedef float f32x4 __attribute__((ext_vector_type(4)));
typedef short short8 __attribute__((ext_vector_type(8)));
typedef unsigned short ushort8 __attribute__((ext_vector_type(8)));

__device__ inline u16 f2bf(float f) {
  unsigned u = __float_as_uint(f);
  unsigned r = (u + 0x7fffu + ((u >> 16) & 1u)) >> 16;
  return (u16)r;
}
__device__ inline float bf2f(u16 v) {
  return __uint_as_float(((unsigned)v) << 16);
}

// ---- merged: KNN (512 thr, 8 pts/block, blocks 0..1023) + weight prep (blocks 1024+) ----
__global__ __launch_bounds__(512) void knn_wcvt(
    const float* __restrict__ x, int* __restrict__ nn,
    const float* __restrict__ w1_3, const float* __restrict__ w2_3,
    const float* __restrict__ w1_2, const float* __restrict__ w2_2,
    const float* __restrict__ hn_w1, const float* __restrict__ f_w,
    const float* __restrict__ he_w1, const float* __restrict__ he_w2,
    const float* __restrict__ bn_w1, const float* __restrict__ bn_w2,
    const float* __restrict__ n2_w1, const float* __restrict__ n2_w2,
    u16* __restrict__ w1b3e, u16* __restrict__ wpq3, u16* __restrict__ w2b3,
    u16* __restrict__ w1b2e, u16* __restrict__ wpq2, u16* __restrict__ w2b2,
    float* __restrict__ w1p1, u16* __restrict__ fwb,
    u16* __restrict__ w1b1, u16* __restrict__ w2b1,
    u16* __restrict__ wn1b, u16* __restrict__ wn2b,
    u16* __restrict__ wn21b, u16* __restrict__ wn22b,
    int* __restrict__ pooled) {
  const int tid = threadIdx.x;
  if (blockIdx.x >= BDIM * 128) {
    const int idx = (blockIdx.x - BDIM * 128) * 512 + tid;
    if (idx < 512 * 384) fwb[idx] = f2bf(f_w[idx]);
    if (idx < 96 * 128) {
      int oc = idx >> 7, c = idx & 127;
      w1b3e[idx] = f2bf(w1_3[oc * 384 + c]);
    }
    if (idx < 192 * 128) {
      int n = idx >> 7, c = idx & 127;
      wpq3[idx] = f2bf(n < 96 ? w1_3[n * 384 + 128 + c]
                              : w1_3[(n - 96) * 384 + 256 + c]);
    }
    if (idx < 192 * 96) w2b3[idx] = f2bf(w2_3[idx]);
    if (idx < 48 * 64) {
      int oc = idx >> 6, c = idx & 63;
      w1b2e[idx] = f2bf(w1_2[oc * 192 + c]);
    }
    if (idx < 96 * 64) {
      int n = idx >> 6, c = idx & 63;
      wpq2[idx] = f2bf(n < 48 ? w1_2[n * 192 + 64 + c]
                              : w1_2[(n - 48) * 192 + 128 + c]);
    }
    if (idx < 128 * 64) {
      int oc = idx >> 6, i = idx & 63;
      w2b2[idx] = (i < 48) ? f2bf(w2_2[oc * 48 + i]) : (u16)0;
    }
    if (idx < 32 * 68) {
      int oc = idx / 68, c = idx - oc * 68;
      w1p1[idx] = (c < 67) ? hn_w1[oc * 67 + c] : 0.0f;
    }
    if (idx < 32 * 32) {
      int oc = idx >> 5, c = idx & 31;
      w1b1[idx] = (c < 12) ? f2bf(he_w1[oc * 12 + c]) : (u16)0;
    }
    if (idx < 64 * 32) w2b1[idx] = f2bf(he_w2[idx]);
    if (idx < 96 * 320) wn1b[idx] = f2bf(bn_w1[idx]);   // b2n_w1 [96][320]
    if (idx < 192 * 96) wn2b[idx] = f2bf(bn_w2[idx]);   // b2n_w2 [192][96]
    if (idx < 48 * 192) wn21b[idx] = f2bf(n2_w1[idx]);  // b1n_w1 [48][192]
    if (idx < 128 * 64) {                               // b1n_w2 [128][48->64]
      int oc = idx >> 6, i = idx & 63;
      wn22b[idx] = (i < 48) ? f2bf(n2_w2[oc * 48 + i]) : (u16)0;
    }
    if (idx < BDIM * 512) pooled[idx] = 0;
    return;
  }
  {
#pragma clang fp contract(off)
    __shared__ float xs0[NDIM], xs1[NDIM], xs2[NDIM], sq[NDIM];
    const int lane = tid & 63;
    const int w = tid >> 6;  // wave 0..7
    const int b = blockIdx.x >> 7;
    const int n = ((blockIdx.x & 127) << 3) + w;
    for (int i = tid; i < NDIM; i += 512) {
      float a0 = x[(b * 3 + 0) * NDIM + i];
      float a1 = x[(b * 3 + 1) * NDIM + i];
      float a2 = x[(b * 3 + 2) * NDIM + i];
      xs0[i] = a0; xs1[i] = a1; xs2[i] = a2;
      sq[i] = (a0 * a0 + a1 * a1) + a2 * a2;
    }
    __syncthreads();
    const float xn0 = xs0[n], xn1 = xs1[n], xn2 = xs2[n], sqn = sq[n];
    float dl[16];
#pragma unroll
    for (int t = 0; t < 16; ++t) {
      int m = t * 64 + lane;
      float dot = (xn0 * xs0[m] + xn1 * xs1[m]) + xn2 * xs2[m];
      dl[t] = (sqn - 2.0f * dot) + sq[m];
    }
    int* nnrow = &nn[(b * NDIM + n) * KNN];
    for (int r = 0; r < KNN; ++r) {
      float bd = dl[0];
      int bt = 0;
#pragma unroll
      for (int t = 1; t < 16; ++t) {
        if (dl[t] < bd) { bd = dl[t]; bt = t; }
      }
      int bi = bt * 64 + lane;
#pragma unroll
      for (int off = 1; off < 64; off <<= 1) {
        float pd = __shfl_xor(bd, off);
        int pi = __shfl_xor(bi, off);
        if (pd < bd || (pd == bd && pi < bi)) { bd = pd; bi = pi; }
      }
      if (lane == 0) nnrow[r] = bi;
      if ((bi & 63) == lane) {
        int wt = bi >> 6;
#pragma unroll
        for (int t = 0; t < 16; ++t) {
          if (t == wt) dl[t] = 3.4e38f;
        }
      }
    }
  }
}

// ---- MFMA edge MP (lean v9): QY buffer aliasing, 2 barriers ----
template <int PTS, int CE, int CMID, int COUT, bool WRITE_E, bool FIRST>
__global__ __launch_bounds__(256) void edge_mfma(
    const u16* __restrict__ eprev, const float* __restrict__ finput,
    const int* __restrict__ nnb, const u16* __restrict__ w1b,
    const float* __restrict__ b1v, const u16* __restrict__ w2b,
    const float* __restrict__ b2v, const u16* __restrict__ pq,
    u16* __restrict__ eout, float* __restrict__ mout) {
  constexpr int K2 = (CMID + 31) & ~31;
  constexpr int NPQ = 2 * CMID;
  constexpr int MT = PTS * KNN;       // 80 edges
  constexpr int MTL = MT / 16;        // 5 M-tiles (exact)
  constexpr int XPB = CE + 8;
  constexpr int QYP = K2 + 8;         // unified Q / Y1 pitch
  __shared__ u16 Xs[MT * XPB];
  __shared__ u16 QY[MT * QYP];        // Q staged here, then overwritten by Y1
  __shared__ float pld[FIRST ? 8 : PTS * CMID];
  const int tid = threadIdx.x;
  const int lane = tid & 63;
  const int wv = tid >> 6;
  const int q = lane >> 4;
  const int bn0 = blockIdx.x * PTS;
  const int b = bn0 >> 10;
  // ---- bulk staging ----
  if constexpr (FIRST) {
    for (int idx = tid; idx < MT * (CE / 8); idx += 256) {
      int p = idx / (CE / 8), kc = idx - p * (CE / 8);
      int k0 = kc * 8;
      int bn = bn0 + p / KNN;
      int n = bn & (NDIM - 1);
      int j = nnb[(size_t)bn0 * KNN + p];
      ushort8 r;
#pragma unroll
      for (int t = 0; t < 8; ++t) {
        int c = k0 + t;
        float v = 0.0f;
        if (c < 3) v = finput[(b * 3 + c) * NDIM + n];
        else if (c < 6)
          v = finput[(b * 3 + c - 3) * NDIM + n] -
              finput[(b * 3 + c - 3) * NDIM + j];
        else if (c < 9) v = finput[(b * 3 + c - 6) * NDIM + n];
        else if (c < 12) v = finput[(b * 3 + c - 9) * NDIM + j];
        r[t] = f2bf(v);
      }
      *(ushort8*)&Xs[p * XPB + k0] = r;
    }
  } else {
    constexpr int KC = CE / 8;
    for (int ch = tid; ch < MT * KC; ch += 256) {
      int p = ch / KC, kc = ch - p * KC;
      int k0 = kc * 8;
      *(uint4*)&Xs[p * XPB + k0] =
          *(const uint4*)&eprev[((size_t)blockIdx.x * MT + p) * CE + k0];
    }
    constexpr int QC = CMID / 8;
    for (int i = tid; i < MT * QC; i += 256) {
      int p = i / QC, c8 = (i - p * QC) * 8;
      int j = nnb[(size_t)bn0 * KNN + p];
      *(uint4*)&QY[p * QYP + c8] =
          *(const uint4*)&pq[((size_t)(b << 10) + j) * NPQ + CMID + c8];
    }
    if constexpr (K2 != CMID) {
      constexpr int PC = (K2 - CMID) / 8;
      for (int i = tid; i < MT * PC; i += 256) {
        int p = i / PC, c8 = CMID + (i - p * PC) * 8;
        uint4 z = {0, 0, 0, 0};
        *(uint4*)&QY[p * QYP + c8] = z;
      }
    }
    for (int i = tid; i < PTS * CMID; i += 256) {
      int pt = i / CMID, c = i - pt * CMID;
      pld[i] = bf2f(pq[(size_t)(bn0 + pt) * NPQ + c]) + b1v[c];
    }
  }
  __syncthreads();
  // ---- conv1: Xs @ W1^T (+P+Q folded) -> relu -> QY (in-place over Q) ----
  {
    constexpr int NT1 = CMID / 16;
    constexpr int J1 = MTL * NT1;
    constexpr int KS1 = CE / 32;
    for (int job = wv; job < J1; job += 4) {
      int mt = job / NT1, nt = job - mt * NT1;
      int row = mt * 16 + (lane & 15);
      int ncol = nt * 16 + (lane & 15);
      int kb = q * 8;
      f32x4 acc = {0.f, 0.f, 0.f, 0.f};
      const u16* ap = &Xs[row * XPB + kb];
      const u16* bp = &w1b[(size_t)ncol * CE + kb];
#pragma unroll
      for (int ks = 0; ks < KS1; ++ks) {
        short8 a = *(const short8*)(ap + ks * 32);
        short8 bb = *(const short8*)(bp + ks * 32);
        acc = __builtin_amdgcn_mfma_f32_16x16x32_bf16(a, bb, acc, 0, 0, 0);
      }
      int m0 = mt * 16 + q * 4;
      if constexpr (FIRST) {
        float bias = b1v[ncol];
#pragma unroll
        for (int r = 0; r < 4; ++r) {
          float yv = fmaxf(acc[r] + bias, 0.0f);
          QY[(m0 + r) * QYP + ncol] = f2bf(yv);
        }
      } else {
        int pt = m0 / KNN;
        float padd = pld[pt * CMID + ncol];
#pragma unroll
        for (int r = 0; r < 4; ++r) {
          int m = m0 + r;
          float qadd = bf2f(QY[m * QYP + ncol]);
          float yv = fmaxf(acc[r] + padd + qadd, 0.0f);
          QY[m * QYP + ncol] = f2bf(yv);
        }
      }
    }
  }
  __syncthreads();
  // ---- conv2: fp32 m-sum, const-folded pt map ----
  {
    constexpr int NT2 = COUT / 16;
    constexpr int KS2 = K2 / 32;
    for (int nt = wv; nt < NT2; nt += 4) {
      int ncol = nt * 16 + (lane & 15);
      int kb = q * 8;
      short8 bfrag[KS2];
      const u16* bp = &w2b[(size_t)ncol * K2 + kb];
#pragma unroll
      for (int ks = 0; ks < KS2; ++ks)
        bfrag[ks] = *(const short8*)(bp + ks * 32);
      float bias = b2v[ncol];
      float s[PTS];
#pragma unroll
      for (int pt = 0; pt < PTS; ++pt) s[pt] = 0.0f;
#pragma unroll
      for (int mt = 0; mt < MTL; ++mt) {
        f32x4 acc = {0.f, 0.f, 0.f, 0.f};
        const u16* ap = &QY[(mt * 16 + (lane & 15)) * QYP + kb];
#pragma unroll
        for (int ks = 0; ks < KS2; ++ks) {
          short8 a = *(const short8*)(ap + ks * 32);
          acc = __builtin_amdgcn_mfma_f32_16x16x32_bf16(a, bfrag[ks], acc, 0, 0, 0);
        }
        int m0 = mt * 16 + q * 4;
        float part = 0.0f;
#pragma unroll
        for (int r = 0; r < 4; ++r) {
          float yv = fmaxf(acc[r] + bias, 0.0f);
          if (WRITE_E)
            eout[((size_t)blockIdx.x * MT + m0 + r) * COUT + ncol] = f2bf(yv);
          part += yv;
        }
        int ptA = (4 * mt) / 5;
        int ptB = (4 * mt + 3) / 5;
        int qb = 5 * ptB - 4 * mt;
#pragma unroll
        for (int pt2 = 0; pt2 < PTS; ++pt2) {
          if (pt2 == ptA && ptA == ptB) s[pt2] += part;
          else if (pt2 == ptA) s[pt2] += (q < qb) ? part : 0.0f;
          else if (pt2 == ptB) s[pt2] += (q < qb) ? 0.0f : part;
        }
      }
#pragma unroll
      for (int pt = 0; pt < PTS; ++pt) {
        float sv = s[pt];
        sv += __shfl_xor(sv, 16);
        sv += __shfl_xor(sv, 32);
        if (lane < 16)
          mout[(size_t)(bn0 + pt) * COUT + nt * 16 + lane] = sv;
      }
    }
  }
}

// ---- node1 conv: fp32 microtile GEMM + fused PQ MFMA phase ----
template <int TP, int CH, int CM, int CINP, int CMID, int COUT, int NPQ, bool FIRSTH>
__global__ __launch_bounds__(256) void node_conv(
    const float* __restrict__ h, const float* __restrict__ inputs,
    const float* __restrict__ mbuf, const float* __restrict__ w1p,
    const float* __restrict__ b1v, const float* __restrict__ w2,
    const float* __restrict__ b2v, float* __restrict__ hout,
    const u16* __restrict__ wpq, u16* __restrict__ pq) {
  constexpr int CIN = CH + CM;
  constexpr int XP = CINP + 4;
  constexpr int Y1P = CMID + 4;
  constexpr int PG = TP / 4;
  constexpr int HP = COUT + 8;
  __shared__ float Xs[TP * XP];
  __shared__ float Y1s[TP * Y1P];
  __shared__ u16 Hb[(NPQ > 0) ? TP * HP : 8];
  const int tid = threadIdx.x;
  const int bn0 = blockIdx.x * TP;
  if constexpr (FIRSTH) {
    for (int idx = tid; idx < TP * CIN; idx += 256) {
      int p = idx / CIN, c = idx - p * CIN;
      int bn = bn0 + p;
      int b = bn >> 10, n = bn & (NDIM - 1);
      Xs[p * XP + c] = (c < CH) ? inputs[(b * 3 + c) * NDIM + n]
                                : mbuf[(size_t)bn * CM + (c - CH)];
    }
    if constexpr (CINP > CIN) {
      constexpr int PAD = CINP - CIN;
      for (int idx = tid; idx < TP * PAD; idx += 256) {
        int p = idx / PAD, c = CIN + idx % PAD;
        Xs[p * XP + c] = 0.0f;
      }
    }
  } else {
    constexpr int C4 = CIN / 4;
    for (int idx = tid; idx < TP * C4; idx += 256) {
      int p = idx / C4, c = (idx - p * C4) * 4;
      int bn = bn0 + p;
      float4 v = (c < CH) ? *(const float4*)&h[(size_t)bn * CH + c]
                          : *(const float4*)&mbuf[(size_t)bn * CM + (c - CH)];
      *(float4*)&Xs[p * XP + c] = v;
    }
  }
  __syncthreads();
  {
    constexpr int NT1 = PG * (CMID / 4);
    for (int t = tid; t < NT1; t += 256) {
      int pg = t % PG, og = t / PG;
      float acc[4][4];
#pragma unroll
      for (int j = 0; j < 4; ++j) {
        float bj = b1v[og * 4 + j];
#pragma unroll
        for (int i = 0; i < 4; ++i) acc[i][j] = bj;
      }
      for (int cin = 0; cin < CINP; cin += 4) {
        float4 xr[4], wr[4];
#pragma unroll
        for (int i = 0; i < 4; ++i)
          xr[i] = *(const float4*)&Xs[(pg * 4 + i) * XP + cin];
#pragma unroll
        for (int j = 0; j < 4; ++j)
          wr[j] = *(const float4*)&w1p[(size_t)(og * 4 + j) * CINP + cin];
#pragma unroll
        for (int i = 0; i < 4; ++i)
#pragma unroll
          for (int j = 0; j < 4; ++j) {
            acc[i][j] += xr[i].x * wr[j].x;
            acc[i][j] += xr[i].y * wr[j].y;
            acc[i][j] += xr[i].z * wr[j].z;
            acc[i][j] += xr[i].w * wr[j].w;
          }
      }
#pragma unroll
      for (int i = 0; i < 4; ++i)
#pragma unroll
        for (int j = 0; j < 4; ++j)
          Y1s[(pg * 4 + i) * Y1P + og * 4 + j] = fmaxf(acc[i][j], 0.0f);
    }
  }
  __syncthreads();
  {
    constexpr int NT2 = PG * (COUT / 4);
    for (int t = tid; t < NT2; t += 256) {
      int pg = t % PG, og = t / PG;
      float acc[4][4];
#pragma unroll
      for (int j = 0; j < 4; ++j) {
        float bj = b2v[og * 4 + j];
#pragma unroll
        for (int i = 0; i < 4; ++i) acc[i][j] = bj;
      }
      for (int cin = 0; cin < CMID; cin += 4) {
        float4 xr[4], wr[4];
#pragma unroll
        for (int i = 0; i < 4; ++i)
          xr[i] = *(const float4*)&Y1s[(pg * 4 + i) * Y1P + cin];
#pragma unroll
        for (int j = 0; j < 4; ++j)
          wr[j] = *(const float4*)&w2[(size_t)(og * 4 + j) * CMID + cin];
#pragma unroll
        for (int i = 0; i < 4; ++i)
#pragma unroll
          for (int j = 0; j < 4; ++j) {
            acc[i][j] += xr[i].x * wr[j].x;
            acc[i][j] += xr[i].y * wr[j].y;
            acc[i][j] += xr[i].z * wr[j].z;
            acc[i][j] += xr[i].w * wr[j].w;
          }
      }
#pragma unroll
      for (int i = 0; i < 4; ++i) {
        int bn = bn0 + pg * 4 + i;
#pragma unroll
        for (int j = 0; j < 4; ++j) {
          float v = fmaxf(acc[i][j], 0.0f);
          hout[(size_t)bn * COUT + og * 4 + j] = v;
          if constexpr (NPQ > 0) Hb[(pg * 4 + i) * HP + og * 4 + j] = f2bf(v);
        }
      }
    }
  }
  if constexpr (NPQ > 0) {
    __syncthreads();
    const int lane = tid & 63;
    const int wv = tid >> 6;
    constexpr int NT = NPQ / 16;
    constexpr int JOBS = (TP / 16) * NT;
    constexpr int KS = COUT / 32;
    for (int job = wv; job < JOBS; job += 4) {
      int mt = job / NT, nt = job - mt * NT;
      int row = mt * 16 + (lane & 15);
      int ncol = nt * 16 + (lane & 15);
      int kb = (lane >> 4) * 8;
      f32x4 acc = {0.f, 0.f, 0.f, 0.f};
      const u16* ap = &Hb[row * HP + kb];
      const u16* bp = &wpq[(size_t)ncol * COUT + kb];
#pragma unroll
      for (int ks = 0; ks < KS; ++ks) {
        short8 a = *(const short8*)(ap + ks * 32);
        short8 bb = *(const short8*)(bp + ks * 32);
        acc = __builtin_amdgcn_mfma_f32_16x16x32_bf16(a, bb, acc, 0, 0, 0);
      }
      int m0 = mt * 16 + (lane >> 4) * 4;
#pragma unroll
      for (int r = 0; r < 4; ++r)
        pq[(size_t)(bn0 + m0 + r) * NPQ + ncol] = f2bf(acc[r]);
    }
  }
}

// ---- node2 conv via MFMA: [h1|m2]->48->128 (h2) + pq3 phase ----
__global__ __launch_bounds__(256) void node2_mfma(
    const float* __restrict__ h1, const float* __restrict__ m2,
    const u16* __restrict__ w1b, const float* __restrict__ b1v,
    const u16* __restrict__ w2b, const float* __restrict__ b2v,
    float* __restrict__ h2out, const u16* __restrict__ wpq,
    u16* __restrict__ pq) {
  constexpr int TP = 32, XP = 200, Y1P = 72, HP = 136;
  __shared__ u16 Xb[TP * XP];
  __shared__ u16 Y1[TP * Y1P];
  __shared__ u16 Hb[TP * HP];
  const int tid = threadIdx.x;
  const int lane = tid & 63;
  const int wv = tid >> 6;
  const int q = lane >> 4;
  const int bn0 = blockIdx.x * TP;
  for (int i = tid; i < TP * 24; i += 256) {
    int p = i / 24, kc = i - p * 24;
    int k0 = kc * 8;
    const float* src = (k0 < 64) ? &h1[(size_t)(bn0 + p) * 64 + k0]
                                 : &m2[(size_t)(bn0 + p) * 128 + (k0 - 64)];
    float4 f0 = *(const float4*)src;
    float4 f1 = *(const float4*)(src + 4);
    ushort8 r;
    r[0] = f2bf(f0.x); r[1] = f2bf(f0.y); r[2] = f2bf(f0.z); r[3] = f2bf(f0.w);
    r[4] = f2bf(f1.x); r[5] = f2bf(f1.y); r[6] = f2bf(f1.z); r[7] = f2bf(f1.w);
    *(ushort8*)&Xb[p * XP + k0] = r;
  }
  for (int i = tid; i < TP * 2; i += 256) {
    int p = i >> 1, c8 = 48 + (i & 1) * 8;
    ushort8 z = {0, 0, 0, 0, 0, 0, 0, 0};
    *(ushort8*)&Y1[p * Y1P + c8] = z;
  }
  __syncthreads();
  for (int job = wv; job < 6; job += 4) {
    int mt = job / 3, nt = job - mt * 3;
    int row = mt * 16 + (lane & 15);
    int ncol = nt * 16 + (lane & 15);
    int kb = q * 8;
    f32x4 acc = {0.f, 0.f, 0.f, 0.f};
    const u16* ap = &Xb[row * XP + kb];
    const u16* bp = &w1b[(size_t)ncol * 192 + kb];
#pragma unroll
    for (int ks = 0; ks < 6; ++ks) {
      short8 a = *(const short8*)(ap + ks * 32);
      short8 bb = *(const short8*)(bp + ks * 32);
      acc = __builtin_amdgcn_mfma_f32_16x16x32_bf16(a, bb, acc, 0, 0, 0);
    }
    float bias = b1v[ncol];
    int m0 = mt * 16 + q * 4;
#pragma unroll
    for (int r = 0; r < 4; ++r)
      Y1[(m0 + r) * Y1P + ncol] = f2bf(fmaxf(acc[r] + bias, 0.0f));
  }
  __syncthreads();
  for (int job = wv; job < 16; job += 4) {
    int mt = job / 8, nt = job - mt * 8;
    int row = mt * 16 + (lane & 15);
    int ncol = nt * 16 + (lane & 15);
    int kb = q * 8;
    f32x4 acc = {0.f, 0.f, 0.f, 0.f};
    const u16* ap = &Y1[row * Y1P + kb];
    const u16* bp = &w2b[(size_t)ncol * 64 + kb];
#pragma unroll
    for (int ks = 0; ks < 2; ++ks) {
      short8 a = *(const short8*)(ap + ks * 32);
      short8 bb = *(const short8*)(bp + ks * 32);
      acc = __builtin_amdgcn_mfma_f32_16x16x32_bf16(a, bb, acc, 0, 0, 0);
    }
    float bias = b2v[ncol];
    int m0 = mt * 16 + q * 4;
#pragma unroll
    for (int r = 0; r < 4; ++r) {
      float v = fmaxf(acc[r] + bias, 0.0f);
      h2out[(size_t)(bn0 + m0 + r) * 128 + ncol] = v;
      Hb[(m0 + r) * HP + ncol] = f2bf(v);
    }
  }
  __syncthreads();
  for (int job = wv; job < 24; job += 4) {
    int mt = job / 12, nt = job - mt * 12;
    int row = mt * 16 + (lane & 15);
    int ncol = nt * 16 + (lane & 15);
    int kb = q * 8;
    f32x4 acc = {0.f, 0.f, 0.f, 0.f};
    const u16* ap = &Hb[row * HP + kb];
    const u16* bp = &wpq[(size_t)ncol * 128 + kb];
#pragma unroll
    for (int ks = 0; ks < 4; ++ks) {
      short8 a = *(const short8*)(ap + ks * 32);
      short8 bb = *(const short8*)(bp + ks * 32);
      acc = __builtin_amdgcn_mfma_f32_16x16x32_bf16(a, bb, acc, 0, 0, 0);
    }
    int m0 = mt * 16 + q * 4;
#pragma unroll
    for (int r = 0; r < 4; ++r)
      pq[(size_t)(bn0 + m0 + r) * 192 + ncol] = f2bf(acc[r]);
  }
}

// ---- fuse_pool v2: fused node3 (h2,m3 -> h3 in LDS) + fusion conv + max pool ----
__global__ __launch_bounds__(256) void fuse_pool_mfma(
    const float* __restrict__ h1, const float* __restrict__ h2,
    const float* __restrict__ m3, const u16* __restrict__ wn1b,
    const float* __restrict__ bn1v, const u16* __restrict__ wn2b,
    const float* __restrict__ bn2v, const u16* __restrict__ fwb,
    const float* __restrict__ fb, int* __restrict__ pooled) {
  constexpr int TP = 32;
  constexpr int XNP = 328;
  constexpr int Y1NP = 104;
  constexpr int XPB = 392;
  __shared__ __align__(16) char smem[TP * XPB * 2];
  u16* Xs = (u16*)smem;
  u16* Xn = (u16*)smem;
  __shared__ u16 Y1n[TP * Y1NP];
  __shared__ int pmax[512];
  const int tid = threadIdx.x;
  const int lane = tid & 63;
  const int wv = tid >> 6;
  const int q = lane >> 4;
  const int bn0 = blockIdx.x * TP;
  const int b = bn0 >> 10;
  for (int i = tid; i < 512; i += 256) pmax[i] = 0;
  for (int i = tid; i < TP * 41; i += 256) {
    int p = i / 41, kc = i - p * 41;
    int k0 = kc * 8;
    ushort8 r;
    if (kc < 16) {
      const float* src = &h2[(size_t)(bn0 + p) * 128 + k0];
      float4 f0 = *(const float4*)src;
      float4 f1 = *(const float4*)(src + 4);
      r[0] = f2bf(f0.x); r[1] = f2bf(f0.y); r[2] = f2bf(f0.z); r[3] = f2bf(f0.w);
      r[4] = f2bf(f1.x); r[5] = f2bf(f1.y); r[6] = f2bf(f1.z); r[7] = f2bf(f1.w);
    } else if (kc < 40) {
      const float* src = &m3[(size_t)(bn0 + p) * 192 + (k0 - 128)];
      float4 f0 = *(const float4*)src;
      float4 f1 = *(const float4*)(src + 4);
      r[0] = f2bf(f0.x); r[1] = f2bf(f0.y); r[2] = f2bf(f0.z); r[3] = f2bf(f0.w);
      r[4] = f2bf(f1.x); r[5] = f2bf(f1.y); r[6] = f2bf(f1.z); r[7] = f2bf(f1.w);
    } else {
#pragma unroll
      for (int t = 0; t < 8; ++t) r[t] = 0;
    }
    *(ushort8*)&Xn[p * XNP + k0] = r;
  }
  __syncthreads();
  for (int job = wv; job < 12; job += 4) {
    int mt = job / 6, nt = job - mt * 6;
    int row = mt * 16 + (lane & 15);
    int ncol = nt * 16 + (lane & 15);
    int kb = q * 8;
    f32x4 acc = {0.f, 0.f, 0.f, 0.f};
    const u16* ap = &Xn[row * XNP + kb];
    const u16* bp = &wn1b[(size_t)ncol * 320 + kb];
#pragma unroll
    for (int ks = 0; ks < 10; ++ks) {
      short8 a = *(const short8*)(ap + ks * 32);
      short8 bb = *(const short8*)(bp + ks * 32);
      acc = __builtin_amdgcn_mfma_f32_16x16x32_bf16(a, bb, acc, 0, 0, 0);
    }
    float bias = bn1v[ncol];
    int m0 = mt * 16 + q * 4;
#pragma unroll
    for (int r = 0; r < 4; ++r)
      Y1n[(m0 + r) * Y1NP + ncol] = f2bf(fmaxf(acc[r] + bias, 0.0f));
  }
  __syncthreads();
  for (int i = tid; i < TP * 24; i += 256) {
    int p = i / 24, kc = i - p * 24;
    int k0 = kc * 8;
    const float* src = (k0 < 64) ? &h1[(size_t)(bn0 + p) * 64 + k0]
                                 : &h2[(size_t)(bn0 + p) * 128 + (k0 - 64)];
    float4 f0 = *(const float4*)src;
    float4 f1 = *(const float4*)(src + 4);
    ushort8 r;
    r[0] = f2bf(f0.x); r[1] = f2bf(f0.y); r[2] = f2bf(f0.z); r[3] = f2bf(f0.w);
    r[4] = f2bf(f1.x); r[5] = f2bf(f1.y); r[6] = f2bf(f1.z); r[7] = f2bf(f1.w);
    *(ushort8*)&Xs[p * XPB + k0] = r;
  }
  if (tid < TP) {
    ushort8 z = {0, 0, 0, 0, 0, 0, 0, 0};
    *(ushort8*)&Xs[tid * XPB + 384] = z;
  }
  for (int job = wv; job < 24; job += 4) {
    int mt = job / 12, nt = job - mt * 12;
    int row = mt * 16 + (lane & 15);
    int ncol = nt * 16 + (lane & 15);
    int kb = q * 8;
    f32x4 acc = {0.f, 0.f, 0.f, 0.f};
    const u16* ap = &Y1n[row * Y1NP + kb];
    const u16* bp = &wn2b[(size_t)ncol * 96 + kb];
#pragma unroll
    for (int ks = 0; ks < 3; ++ks) {
      short8 a = *(const short8*)(ap + ks * 32);
      short8 bb = *(const short8*)(bp + ks * 32);
      acc = __builtin_amdgcn_mfma_f32_16x16x32_bf16(a, bb, acc, 0, 0, 0);
    }
    float bias = bn2v[ncol];
    int m0 = mt * 16 + q * 4;
#pragma unroll
    for (int r = 0; r < 4; ++r)
      Xs[(m0 + r) * XPB + 192 + ncol] = f2bf(fmaxf(acc[r] + bias, 0.0f));
  }
  __syncthreads();
  for (int job = wv; job < 64; job += 4) {
    int mt = job / 32, nt = job - mt * 32;
    int row = mt * 16 + (lane & 15);
    int ncol = nt * 16 + (lane & 15);
    int kb = q * 8;
    f32x4 acc = {0.f, 0.f, 0.f, 0.f};
    const u16* ap = &Xs[row * XPB + kb];
    const u16* bp = &fwb[(size_t)ncol * 384 + kb];
#pragma unroll
    for (int ks = 0; ks < 12; ++ks) {
      short8 a = *(const short8*)(ap + ks * 32);
      short8 bb = *(const short8*)(bp + ks * 32);
      acc = __builtin_amdgcn_mfma_f32_16x16x32_bf16(a, bb, acc, 0, 0, 0);
    }
    float bias = fb[ncol];
    float v = fmaxf(fmaxf(acc[0], acc[1]), fmaxf(acc[2], acc[3]));
    v = fmaxf(v + bias, 0.0f);
    v = fmaxf(v, __shfl_xor(v, 16));
    v = fmaxf(v, __shfl_xor(v, 32));
    if (lane < 16) atomicMax(&pmax[ncol], __float_as_int(v));
  }
  __syncthreads();
  for (int i = tid; i < 512; i += 256)
    atomicMax(&pooled[b * 512 + i], pmax[i]);
}

// ---------------- prediction head (blocks 0..7) + inputs echo copy (blocks 8+) ----------------
__global__ __launch_bounds__(256) void head_kernel(
    const int* __restrict__ pooledi, const float* __restrict__ p1w,
    const float* __restrict__ p1b, const float* __restrict__ p2w,
    const float* __restrict__ p2b, const float* __restrict__ p3w,
    const float* __restrict__ p3b, const float* __restrict__ inputs,
    float* __restrict__ out) {
  const int tid = threadIdx.x;
  if (blockIdx.x >= BDIM) {
    int idx = (blockIdx.x - BDIM) * 256 + tid;
    if (idx < (BDIM * 3 * NDIM) / 4) {
      const float4* src = (const float4*)inputs;
      float4* dst = (float4*)(out + BDIM * 40);
      dst[idx] = src[idx];
    }
    return;
  }
  __shared__ float xs[512], y1[256], y2[128];
  const int b = blockIdx.x;
  for (int i = tid; i < 512; i += 256) xs[i] = __int_as_float(pooledi[b * 512 + i]);
  __syncthreads();
  {
    float acc = p1b[tid];
    for (int c = 0; c < 512; ++c) acc += xs[c] * p1w[tid * 512 + c];
    y1[tid] = fmaxf(acc, 0.0f);
  }
  __syncthreads();
  if (tid < 128) {
    float acc = p2b[tid];
    for (int c = 0; c < 256; ++c) acc += y1[c] * p2w[tid * 256 + c];
    y2[tid] = fmaxf(acc, 0.0f);
  }
  __syncthreads();
  if (tid < 40) {
    float acc = p3b[tid];
    for (int c = 0; c < 128; ++c) acc += y2[c] * p3w[tid * 128 + c];
    out[b * 40 + tid] = acc;
  }
}

extern "C" void kernel_launch(void* const* d_in, const int* in_sizes, int n_in,
                              void* d_out, int out_size, void* d_ws,
                              size_t ws_size, hipStream_t stream) {
  const float* inputs = (const float*)d_in[0];
  const float* he_w1 = (const float*)d_in[1];
  const float* he_b1 = (const float*)d_in[2];
  const float* he_w2 = (const float*)d_in[3];
  const float* he_b2 = (const float*)d_in[4];
  const float* hn_w1 = (const float*)d_in[5];
  const float* hn_b1 = (const float*)d_in[6];
  const float* hn_w2 = (const float*)d_in[7];
  const float* hn_b2 = (const float*)d_in[8];
  const float* b1e_w1 = (const float*)d_in[9];
  const float* b1e_b1 = (const float*)d_in[10];
  const float* b1e_w2 = (const float*)d_in[11];
  const float* b1e_b2 = (const float*)d_in[12];
  const float* b1n_w1 = (const float*)d_in[13];
  const float* b1n_b1 = (const float*)d_in[14];
  const float* b1n_w2 = (const float*)d_in[15];
  const float* b1n_b2 = (const float*)d_in[16];
  const float* b2e_w1 = (const float*)d_in[17];
  const float* b2e_b1 = (const float*)d_in[18];
  const float* b2e_w2 = (const float*)d_in[19];
  const float* b2e_b2 = (const float*)d_in[20];
  const float* b2n_w1 = (const float*)d_in[21];
  const float* b2n_b1 = (const float*)d_in[22];
  const float* b2n_w2 = (const float*)d_in[23];
  const float* b2n_b2 = (const float*)d_in[24];
  const float* f_w = (const float*)d_in[25];
  const float* f_b = (const float*)d_in[26];
  const float* p1_w = (const float*)d_in[27];
  const float* p1_b = (const float*)d_in[28];
  const float* p2_w = (const float*)d_in[29];
  const float* p2_b = (const float*)d_in[30];
  const float* p3_w = (const float*)d_in[31];
  const float* p3_b = (const float*)d_in[32];
  float* out = (float*)d_out;

  char* ws = (char*)d_ws;
  size_t off = 0;
  auto alloc = [&](size_t bytes) {
    void* p = ws + off;
    off += (bytes + 255) & ~(size_t)255;
    return p;
  };
  int* nn = (int*)alloc((size_t)BDIM * NDIM * KNN * 4);
  float* m1 = (float*)alloc((size_t)BDIM * NDIM * 64 * 4);
  float* h1 = (float*)alloc((size_t)BDIM * NDIM * 64 * 4);
  u16* e1 = (u16*)alloc((size_t)BDIM * NDIM * KNN * 64 * 2);   // bf16
  float* m2 = (float*)alloc((size_t)BDIM * NDIM * 128 * 4);
  float* h2 = (float*)alloc((size_t)BDIM * NDIM * 128 * 4);
  u16* e2 = (u16*)alloc((size_t)BDIM * NDIM * KNN * 128 * 2);  // bf16
  float* m3 = (float*)alloc((size_t)BDIM * NDIM * 192 * 4);
  u16* pq2 = (u16*)alloc((size_t)BDIM * NDIM * 96 * 2);        // bf16
  u16* pq3 = (u16*)alloc((size_t)BDIM * NDIM * 192 * 2);       // bf16
  int* pooled = (int*)alloc((size_t)BDIM * 512 * 4);
  u16* w1b3e = (u16*)alloc((size_t)96 * 128 * 2);
  u16* wpq3 = (u16*)alloc((size_t)192 * 128 * 2);
  u16* w2b3 = (u16*)alloc((size_t)192 * 96 * 2);
  u16* w1b2e = (u16*)alloc((size_t)48 * 64 * 2);
  u16* wpq2 = (u16*)alloc((size_t)96 * 64 * 2);
  u16* w2b2 = (u16*)alloc((size_t)128 * 64 * 2);
  float* w1p1 = (float*)alloc((size_t)32 * 68 * 4);
  u16* fwb = (u16*)alloc((size_t)512 * 384 * 2);
  u16* w1b1 = (u16*)alloc((size_t)32 * 32 * 2);
  u16* w2b1 = (u16*)alloc((size_t)64 * 32 * 2);
  u16* wn1b = (u16*)alloc((size_t)96 * 320 * 2);
  u16* wn2b = (u16*)alloc((size_t)192 * 96 * 2);
  u16* wn21b = (u16*)alloc((size_t)48 * 192 * 2);
  u16* wn22b = (u16*)alloc((size_t)128 * 64 * 2);

  knn_wcvt<<<BDIM * 128 + 384, 512, 0, stream>>>(
      inputs, nn, b2e_w1, b2e_w2, b1e_w1, b1e_w2, hn_w1, f_w, he_w1, he_w2,
      b2n_w1, b2n_w2, b1n_w1, b1n_w2, w1b3e, wpq3, w2b3, w1b2e, wpq2, w2b2,
      w1p1, fwb, w1b1, w2b1, wn1b, wn2b, wn21b, wn22b, pooled);

  edge_mfma<4, 32, 32, 64, true, true><<<BDIM * NDIM / 4, 256, 0, stream>>>(
      nullptr, inputs, nn, w1b1, he_b1, w2b1, he_b2, nullptr, e1, m1);
  node_conv<64, 3, 64, 68, 32, 64, 96, true><<<BDIM * NDIM / 64, 256, 0, stream>>>(
      nullptr, inputs, m1, w1p1, hn_b1, hn_w2, hn_b2, h1, wpq2, pq2);

  edge_mfma<4, 64, 48, 128, true, false><<<BDIM * NDIM / 4, 256, 0, stream>>>(
      e1, nullptr, nn, w1b2e, b1e_b1, w2b2, b1e_b2, pq2, e2, m2);
  node2_mfma<<<BDIM * NDIM / 32, 256, 0, stream>>>(
      h1, m2, wn21b, b1n_b1, wn22b, b1n_b2, h2, wpq3, pq3);

  edge_mfma<4, 128, 96, 192, false, false><<<BDIM * NDIM / 4, 256, 0, stream>>>(
      e2, nullptr, nn, w1b3e, b2e_b1, w2b3, b2e_b2, pq3, nullptr, m3);

  fuse_pool_mfma<<<BDIM * NDIM / 32, 256, 0, stream>>>(
      h1, h2, m3, wn1b, b2n_b1, wn2b, b2n_b2, fwb, f_b, pooled);
  head_kernel<<<BDIM + 24, 256, 0, stream>>>(pooled, p1_w, p1_b, p2_w, p2_b,
                                             p3_w, p3_b, inputs, out);
}

// Round 21
// 212.932 us; speedup vs baseline: 1.0423x; 1.0070x over previous
//
#include <hip/hip_runtime.h>

#define BDIM 8
#define NDIM 1024
#define KNN 20

typedef unsigned short u16;
typedef float f32x4 __attribute__((ext_vector_type(4)));
typedef short short8 __attribute__((ext_vector_type(8)));
typedef unsigned short ushort8 __attribute__((ext_vector_type(8)));

__device__ inline u16 f2bf(float f) {
  unsigned u = __float_as_uint(f);
  unsigned r = (u + 0x7fffu + ((u >> 16) & 1u)) >> 16;
  return (u16)r;
}
__device__ inline float bf2f(u16 v) {
  return __uint_as_float(((unsigned)v) << 16);
}

// ---- merged: KNN (512 thr, 8 pts/block, blocks 0..1023) + weight prep (blocks 1024+) ----
__global__ __launch_bounds__(512) void knn_wcvt(
    const float* __restrict__ x, int* __restrict__ nn,
    const float* __restrict__ w1_3, const float* __restrict__ w2_3,
    const float* __restrict__ w1_2, const float* __restrict__ w2_2,
    const float* __restrict__ hn_w1, const float* __restrict__ f_w,
    const float* __restrict__ he_w1, const float* __restrict__ he_w2,
    const float* __restrict__ bn_w1, const float* __restrict__ bn_w2,
    const float* __restrict__ n2_w1, const float* __restrict__ n2_w2,
    u16* __restrict__ w1b3e, u16* __restrict__ wpq3, u16* __restrict__ w2b3,
    u16* __restrict__ w1b2e, u16* __restrict__ wpq2, u16* __restrict__ w2b2,
    float* __restrict__ w1p1, u16* __restrict__ fwb,
    u16* __restrict__ w1b1, u16* __restrict__ w2b1,
    u16* __restrict__ wn1b, u16* __restrict__ wn2b,
    u16* __restrict__ wn21b, u16* __restrict__ wn22b,
    int* __restrict__ pooled) {
  const int tid = threadIdx.x;
  if (blockIdx.x >= BDIM * 128) {
    const int idx = (blockIdx.x - BDIM * 128) * 512 + tid;
    if (idx < 512 * 384) fwb[idx] = f2bf(f_w[idx]);
    if (idx < 96 * 128) {
      int oc = idx >> 7, c = idx & 127;
      w1b3e[idx] = f2bf(w1_3[oc * 384 + c]);
    }
    if (idx < 192 * 128) {
      int n = idx >> 7, c = idx & 127;
      wpq3[idx] = f2bf(n < 96 ? w1_3[n * 384 + 128 + c]
                              : w1_3[(n - 96) * 384 + 256 + c]);
    }
    if (idx < 192 * 96) w2b3[idx] = f2bf(w2_3[idx]);
    if (idx < 48 * 64) {
      int oc = idx >> 6, c = idx & 63;
      w1b2e[idx] = f2bf(w1_2[oc * 192 + c]);
    }
    if (idx < 96 * 64) {
      int n = idx >> 6, c = idx & 63;
      wpq2[idx] = f2bf(n < 48 ? w1_2[n * 192 + 64 + c]
                              : w1_2[(n - 48) * 192 + 128 + c]);
    }
    if (idx < 128 * 64) {
      int oc = idx >> 6, i = idx & 63;
      w2b2[idx] = (i < 48) ? f2bf(w2_2[oc * 48 + i]) : (u16)0;
    }
    if (idx < 32 * 68) {
      int oc = idx / 68, c = idx - oc * 68;
      w1p1[idx] = (c < 67) ? hn_w1[oc * 67 + c] : 0.0f;
    }
    if (idx < 32 * 32) {
      int oc = idx >> 5, c = idx & 31;
      w1b1[idx] = (c < 12) ? f2bf(he_w1[oc * 12 + c]) : (u16)0;
    }
    if (idx < 64 * 32) w2b1[idx] = f2bf(he_w2[idx]);
    if (idx < 96 * 320) wn1b[idx] = f2bf(bn_w1[idx]);   // b2n_w1 [96][320]
    if (idx < 192 * 96) wn2b[idx] = f2bf(bn_w2[idx]);   // b2n_w2 [192][96]
    if (idx < 48 * 192) wn21b[idx] = f2bf(n2_w1[idx]);  // b1n_w1 [48][192]
    if (idx < 128 * 64) {                               // b1n_w2 [128][48->64]
      int oc = idx >> 6, i = idx & 63;
      wn22b[idx] = (i < 48) ? f2bf(n2_w2[oc * 48 + i]) : (u16)0;
    }
    if (idx < BDIM * 512) pooled[idx] = 0;
    return;
  }
  {
#pragma clang fp contract(off)
    __shared__ float xs0[NDIM], xs1[NDIM], xs2[NDIM], sq[NDIM];
    const int lane = tid & 63;
    const int w = tid >> 6;  // wave 0..7
    const int b = blockIdx.x >> 7;
    const int n = ((blockIdx.x & 127) << 3) + w;
    for (int i = tid; i < NDIM; i += 512) {
      float a0 = x[(b * 3 + 0) * NDIM + i];
      float a1 = x[(b * 3 + 1) * NDIM + i];
      float a2 = x[(b * 3 + 2) * NDIM + i];
      xs0[i] = a0; xs1[i] = a1; xs2[i] = a2;
      sq[i] = (a0 * a0 + a1 * a1) + a2 * a2;
    }
    __syncthreads();
    const float xn0 = xs0[n], xn1 = xs1[n], xn2 = xs2[n], sqn = sq[n];
    float dl[16];
#pragma unroll
    for (int t = 0; t < 16; ++t) {
      int m = t * 64 + lane;
      float dot = (xn0 * xs0[m] + xn1 * xs1[m]) + xn2 * xs2[m];
      dl[t] = (sqn - 2.0f * dot) + sq[m];
    }
    int* nnrow = &nn[(b * NDIM + n) * KNN];
    for (int r = 0; r < KNN; ++r) {
      float bd = dl[0];
      int bt = 0;
#pragma unroll
      for (int t = 1; t < 16; ++t) {
        if (dl[t] < bd) { bd = dl[t]; bt = t; }
      }
      int bi = bt * 64 + lane;
#pragma unroll
      for (int off = 1; off < 64; off <<= 1) {
        float pd = __shfl_xor(bd, off);
        int pi = __shfl_xor(bi, off);
        if (pd < bd || (pd == bd && pi < bi)) { bd = pd; bi = pi; }
      }
      if (lane == 0) nnrow[r] = bi;
      if ((bi & 63) == lane) {
        int wt = bi >> 6;
#pragma unroll
        for (int t = 0; t < 16; ++t) {
          if (t == wt) dl[t] = 3.4e38f;
        }
      }
    }
  }
}

// ---- MFMA edge MP (lean v9): QY buffer aliasing, 2 barriers ----
// mout: fp32 when FIRST (m1, consumed fp32), bf16 otherwise (m2/m3, consumed bf16)
template <int PTS, int CE, int CMID, int COUT, bool WRITE_E, bool FIRST>
__global__ __launch_bounds__(256) void edge_mfma(
    const u16* __restrict__ eprev, const float* __restrict__ finput,
    const int* __restrict__ nnb, const u16* __restrict__ w1b,
    const float* __restrict__ b1v, const u16* __restrict__ w2b,
    const float* __restrict__ b2v, const u16* __restrict__ pq,
    u16* __restrict__ eout, void* __restrict__ mout_v) {
  constexpr int K2 = (CMID + 31) & ~31;
  constexpr int NPQ = 2 * CMID;
  constexpr int MT = PTS * KNN;       // 80 edges
  constexpr int MTL = MT / 16;        // 5 M-tiles (exact)
  constexpr int XPB = CE + 8;
  constexpr int QYP = K2 + 8;         // unified Q / Y1 pitch
  __shared__ u16 Xs[MT * XPB];
  __shared__ u16 QY[MT * QYP];        // Q staged here, then overwritten by Y1
  __shared__ float pld[FIRST ? 8 : PTS * CMID];
  const int tid = threadIdx.x;
  const int lane = tid & 63;
  const int wv = tid >> 6;
  const int q = lane >> 4;
  const int bn0 = blockIdx.x * PTS;
  const int b = bn0 >> 10;
  // ---- bulk staging ----
  if constexpr (FIRST) {
    for (int idx = tid; idx < MT * (CE / 8); idx += 256) {
      int p = idx / (CE / 8), kc = idx - p * (CE / 8);
      int k0 = kc * 8;
      int bn = bn0 + p / KNN;
      int n = bn & (NDIM - 1);
      int j = nnb[(size_t)bn0 * KNN + p];
      ushort8 r;
#pragma unroll
      for (int t = 0; t < 8; ++t) {
        int c = k0 + t;
        float v = 0.0f;
        if (c < 3) v = finput[(b * 3 + c) * NDIM + n];
        else if (c < 6)
          v = finput[(b * 3 + c - 3) * NDIM + n] -
              finput[(b * 3 + c - 3) * NDIM + j];
        else if (c < 9) v = finput[(b * 3 + c - 6) * NDIM + n];
        else if (c < 12) v = finput[(b * 3 + c - 9) * NDIM + j];
        r[t] = f2bf(v);
      }
      *(ushort8*)&Xs[p * XPB + k0] = r;
    }
  } else {
    constexpr int KC = CE / 8;
    for (int ch = tid; ch < MT * KC; ch += 256) {
      int p = ch / KC, kc = ch - p * KC;
      int k0 = kc * 8;
      *(uint4*)&Xs[p * XPB + k0] =
          *(const uint4*)&eprev[((size_t)blockIdx.x * MT + p) * CE + k0];
    }
    constexpr int QC = CMID / 8;
    for (int i = tid; i < MT * QC; i += 256) {
      int p = i / QC, c8 = (i - p * QC) * 8;
      int j = nnb[(size_t)bn0 * KNN + p];
      *(uint4*)&QY[p * QYP + c8] =
          *(const uint4*)&pq[((size_t)(b << 10) + j) * NPQ + CMID + c8];
    }
    if constexpr (K2 != CMID) {
      constexpr int PC = (K2 - CMID) / 8;
      for (int i = tid; i < MT * PC; i += 256) {
        int p = i / PC, c8 = CMID + (i - p * PC) * 8;
        uint4 z = {0, 0, 0, 0};
        *(uint4*)&QY[p * QYP + c8] = z;
      }
    }
    for (int i = tid; i < PTS * CMID; i += 256) {
      int pt = i / CMID, c = i - pt * CMID;
      pld[i] = bf2f(pq[(size_t)(bn0 + pt) * NPQ + c]) + b1v[c];
    }
  }
  __syncthreads();
  // ---- conv1: Xs @ W1^T (+P+Q folded) -> relu -> QY (in-place over Q) ----
  {
    constexpr int NT1 = CMID / 16;
    constexpr int J1 = MTL * NT1;
    constexpr int KS1 = CE / 32;
    for (int job = wv; job < J1; job += 4) {
      int mt = job / NT1, nt = job - mt * NT1;
      int row = mt * 16 + (lane & 15);
      int ncol = nt * 16 + (lane & 15);
      int kb = q * 8;
      f32x4 acc = {0.f, 0.f, 0.f, 0.f};
      const u16* ap = &Xs[row * XPB + kb];
      const u16* bp = &w1b[(size_t)ncol * CE + kb];
#pragma unroll
      for (int ks = 0; ks < KS1; ++ks) {
        short8 a = *(const short8*)(ap + ks * 32);
        short8 bb = *(const short8*)(bp + ks * 32);
        acc = __builtin_amdgcn_mfma_f32_16x16x32_bf16(a, bb, acc, 0, 0, 0);
      }
      int m0 = mt * 16 + q * 4;
      if constexpr (FIRST) {
        float bias = b1v[ncol];
#pragma unroll
        for (int r = 0; r < 4; ++r) {
          float yv = fmaxf(acc[r] + bias, 0.0f);
          QY[(m0 + r) * QYP + ncol] = f2bf(yv);
        }
      } else {
        int pt = m0 / KNN;
        float padd = pld[pt * CMID + ncol];
#pragma unroll
        for (int r = 0; r < 4; ++r) {
          int m = m0 + r;
          float qadd = bf2f(QY[m * QYP + ncol]);
          float yv = fmaxf(acc[r] + padd + qadd, 0.0f);
          QY[m * QYP + ncol] = f2bf(yv);
        }
      }
    }
  }
  __syncthreads();
  // ---- conv2: fp32 m-sum, const-folded pt map ----
  {
    constexpr int NT2 = COUT / 16;
    constexpr int KS2 = K2 / 32;
    for (int nt = wv; nt < NT2; nt += 4) {
      int ncol = nt * 16 + (lane & 15);
      int kb = q * 8;
      short8 bfrag[KS2];
      const u16* bp = &w2b[(size_t)ncol * K2 + kb];
#pragma unroll
      for (int ks = 0; ks < KS2; ++ks)
        bfrag[ks] = *(const short8*)(bp + ks * 32);
      float bias = b2v[ncol];
      float s[PTS];
#pragma unroll
      for (int pt = 0; pt < PTS; ++pt) s[pt] = 0.0f;
#pragma unroll
      for (int mt = 0; mt < MTL; ++mt) {
        f32x4 acc = {0.f, 0.f, 0.f, 0.f};
        const u16* ap = &QY[(mt * 16 + (lane & 15)) * QYP + kb];
#pragma unroll
        for (int ks = 0; ks < KS2; ++ks) {
          short8 a = *(const short8*)(ap + ks * 32);
          acc = __builtin_amdgcn_mfma_f32_16x16x32_bf16(a, bfrag[ks], acc, 0, 0, 0);
        }
        int m0 = mt * 16 + q * 4;
        float part = 0.0f;
#pragma unroll
        for (int r = 0; r < 4; ++r) {
          float yv = fmaxf(acc[r] + bias, 0.0f);
          if (WRITE_E)
            eout[((size_t)blockIdx.x * MT + m0 + r) * COUT + ncol] = f2bf(yv);
          part += yv;
        }
        int ptA = (4 * mt) / 5;
        int ptB = (4 * mt + 3) / 5;
        int qb = 5 * ptB - 4 * mt;
#pragma unroll
        for (int pt2 = 0; pt2 < PTS; ++pt2) {
          if (pt2 == ptA && ptA == ptB) s[pt2] += part;
          else if (pt2 == ptA) s[pt2] += (q < qb) ? part : 0.0f;
          else if (pt2 == ptB) s[pt2] += (q < qb) ? 0.0f : part;
        }
      }
#pragma unroll
      for (int pt = 0; pt < PTS; ++pt) {
        float sv = s[pt];
        sv += __shfl_xor(sv, 16);
        sv += __shfl_xor(sv, 32);
        if (lane < 16) {
          size_t o = (size_t)(bn0 + pt) * COUT + nt * 16 + lane;
          if constexpr (FIRST)
            ((float*)mout_v)[o] = sv;
          else
            ((u16*)mout_v)[o] = f2bf(sv);
        }
      }
    }
  }
}

// ---- node1 conv: fp32 microtile GEMM + fused PQ MFMA phase; h1 out bf16 ----
template <int TP, int CH, int CM, int CINP, int CMID, int COUT, int NPQ, bool FIRSTH>
__global__ __launch_bounds__(256) void node_conv(
    const float* __restrict__ h, const float* __restrict__ inputs,
    const float* __restrict__ mbuf, const float* __restrict__ w1p,
    const float* __restrict__ b1v, const float* __restrict__ w2,
    const float* __restrict__ b2v, u16* __restrict__ hout,
    const u16* __restrict__ wpq, u16* __restrict__ pq) {
  constexpr int CIN = CH + CM;
  constexpr int XP = CINP + 4;
  constexpr int Y1P = CMID + 4;
  constexpr int PG = TP / 4;
  constexpr int HP = COUT + 8;
  __shared__ float Xs[TP * XP];
  __shared__ float Y1s[TP * Y1P];
  __shared__ u16 Hb[(NPQ > 0) ? TP * HP : 8];
  const int tid = threadIdx.x;
  const int bn0 = blockIdx.x * TP;
  if constexpr (FIRSTH) {
    for (int idx = tid; idx < TP * CIN; idx += 256) {
      int p = idx / CIN, c = idx - p * CIN;
      int bn = bn0 + p;
      int b = bn >> 10, n = bn & (NDIM - 1);
      Xs[p * XP + c] = (c < CH) ? inputs[(b * 3 + c) * NDIM + n]
                                : mbuf[(size_t)bn * CM + (c - CH)];
    }
    if constexpr (CINP > CIN) {
      constexpr int PAD = CINP - CIN;
      for (int idx = tid; idx < TP * PAD; idx += 256) {
        int p = idx / PAD, c = CIN + idx % PAD;
        Xs[p * XP + c] = 0.0f;
      }
    }
  } else {
    constexpr int C4 = CIN / 4;
    for (int idx = tid; idx < TP * C4; idx += 256) {
      int p = idx / C4, c = (idx - p * C4) * 4;
      int bn = bn0 + p;
      float4 v = (c < CH) ? *(const float4*)&h[(size_t)bn * CH + c]
                          : *(const float4*)&mbuf[(size_t)bn * CM + (c - CH)];
      *(float4*)&Xs[p * XP + c] = v;
    }
  }
  __syncthreads();
  {
    constexpr int NT1 = PG * (CMID / 4);
    for (int t = tid; t < NT1; t += 256) {
      int pg = t % PG, og = t / PG;
      float acc[4][4];
#pragma unroll
      for (int j = 0; j < 4; ++j) {
        float bj = b1v[og * 4 + j];
#pragma unroll
        for (int i = 0; i < 4; ++i) acc[i][j] = bj;
      }
      for (int cin = 0; cin < CINP; cin += 4) {
        float4 xr[4], wr[4];
#pragma unroll
        for (int i = 0; i < 4; ++i)
          xr[i] = *(const float4*)&Xs[(pg * 4 + i) * XP + cin];
#pragma unroll
        for (int j = 0; j < 4; ++j)
          wr[j] = *(const float4*)&w1p[(size_t)(og * 4 + j) * CINP + cin];
#pragma unroll
        for (int i = 0; i < 4; ++i)
#pragma unroll
          for (int j = 0; j < 4; ++j) {
            acc[i][j] += xr[i].x * wr[j].x;
            acc[i][j] += xr[i].y * wr[j].y;
            acc[i][j] += xr[i].z * wr[j].z;
            acc[i][j] += xr[i].w * wr[j].w;
          }
      }
#pragma unroll
      for (int i = 0; i < 4; ++i)
#pragma unroll
        for (int j = 0; j < 4; ++j)
          Y1s[(pg * 4 + i) * Y1P + og * 4 + j] = fmaxf(acc[i][j], 0.0f);
    }
  }
  __syncthreads();
  {
    constexpr int NT2 = PG * (COUT / 4);
    for (int t = tid; t < NT2; t += 256) {
      int pg = t % PG, og = t / PG;
      float acc[4][4];
#pragma unroll
      for (int j = 0; j < 4; ++j) {
        float bj = b2v[og * 4 + j];
#pragma unroll
        for (int i = 0; i < 4; ++i) acc[i][j] = bj;
      }
      for (int cin = 0; cin < CMID; cin += 4) {
        float4 xr[4], wr[4];
#pragma unroll
        for (int i = 0; i < 4; ++i)
          xr[i] = *(const float4*)&Y1s[(pg * 4 + i) * Y1P + cin];
#pragma unroll
        for (int j = 0; j < 4; ++j)
          wr[j] = *(const float4*)&w2[(size_t)(og * 4 + j) * CMID + cin];
#pragma unroll
        for (int i = 0; i < 4; ++i)
#pragma unroll
          for (int j = 0; j < 4; ++j) {
            acc[i][j] += xr[i].x * wr[j].x;
            acc[i][j] += xr[i].y * wr[j].y;
            acc[i][j] += xr[i].z * wr[j].z;
            acc[i][j] += xr[i].w * wr[j].w;
          }
      }
#pragma unroll
      for (int i = 0; i < 4; ++i) {
        int bn = bn0 + pg * 4 + i;
#pragma unroll
        for (int j = 0; j < 4; ++j) {
          float v = fmaxf(acc[i][j], 0.0f);
          u16 bv = f2bf(v);
          hout[(size_t)bn * COUT + og * 4 + j] = bv;
          if constexpr (NPQ > 0) Hb[(pg * 4 + i) * HP + og * 4 + j] = bv;
        }
      }
    }
  }
  if constexpr (NPQ > 0) {
    __syncthreads();
    const int lane = tid & 63;
    const int wv = tid >> 6;
    constexpr int NT = NPQ / 16;
    constexpr int JOBS = (TP / 16) * NT;
    constexpr int KS = COUT / 32;
    for (int job = wv; job < JOBS; job += 4) {
      int mt = job / NT, nt = job - mt * NT;
      int row = mt * 16 + (lane & 15);
      int ncol = nt * 16 + (lane & 15);
      int kb = (lane >> 4) * 8;
      f32x4 acc = {0.f, 0.f, 0.f, 0.f};
      const u16* ap = &Hb[row * HP + kb];
      const u16* bp = &wpq[(size_t)ncol * COUT + kb];
#pragma unroll
      for (int ks = 0; ks < KS; ++ks) {
        short8 a = *(const short8*)(ap + ks * 32);
        short8 bb = *(const short8*)(bp + ks * 32);
        acc = __builtin_amdgcn_mfma_f32_16x16x32_bf16(a, bb, acc, 0, 0, 0);
      }
      int m0 = mt * 16 + (lane >> 4) * 4;
#pragma unroll
      for (int r = 0; r < 4; ++r)
        pq[(size_t)(bn0 + m0 + r) * NPQ + ncol] = f2bf(acc[r]);
    }
  }
}

// ---- node2 conv via MFMA: [h1|m2] (both bf16) ->48->128 (h2 bf16) + pq3 phase ----
__global__ __launch_bounds__(256) void node2_mfma(
    const u16* __restrict__ h1, const u16* __restrict__ m2,
    const u16* __restrict__ w1b, const float* __restrict__ b1v,
    const u16* __restrict__ w2b, const float* __restrict__ b2v,
    u16* __restrict__ h2out, const u16* __restrict__ wpq,
    u16* __restrict__ pq) {
  constexpr int TP = 32, XP = 200, Y1P = 72, HP = 136;
  __shared__ u16 Xb[TP * XP];
  __shared__ u16 Y1[TP * Y1P];
  __shared__ u16 Hb[TP * HP];
  const int tid = threadIdx.x;
  const int lane = tid & 63;
  const int wv = tid >> 6;
  const int q = lane >> 4;
  const int bn0 = blockIdx.x * TP;
  // stage X = [h1(64) | m2(128)] bf16: pure copies
  for (int i = tid; i < TP * 24; i += 256) {
    int p = i / 24, kc = i - p * 24;
    int k0 = kc * 8;
    const u16* src = (k0 < 64) ? &h1[(size_t)(bn0 + p) * 64 + k0]
                               : &m2[(size_t)(bn0 + p) * 128 + (k0 - 64)];
    *(uint4*)&Xb[p * XP + k0] = *(const uint4*)src;
  }
  for (int i = tid; i < TP * 2; i += 256) {
    int p = i >> 1, c8 = 48 + (i & 1) * 8;
    ushort8 z = {0, 0, 0, 0, 0, 0, 0, 0};
    *(ushort8*)&Y1[p * Y1P + c8] = z;
  }
  __syncthreads();
  for (int job = wv; job < 6; job += 4) {
    int mt = job / 3, nt = job - mt * 3;
    int row = mt * 16 + (lane & 15);
    int ncol = nt * 16 + (lane & 15);
    int kb = q * 8;
    f32x4 acc = {0.f, 0.f, 0.f, 0.f};
    const u16* ap = &Xb[row * XP + kb];
    const u16* bp = &w1b[(size_t)ncol * 192 + kb];
#pragma unroll
    for (int ks = 0; ks < 6; ++ks) {
      short8 a = *(const short8*)(ap + ks * 32);
      short8 bb = *(const short8*)(bp + ks * 32);
      acc = __builtin_amdgcn_mfma_f32_16x16x32_bf16(a, bb, acc, 0, 0, 0);
    }
    float bias = b1v[ncol];
    int m0 = mt * 16 + q * 4;
#pragma unroll
    for (int r = 0; r < 4; ++r)
      Y1[(m0 + r) * Y1P + ncol] = f2bf(fmaxf(acc[r] + bias, 0.0f));
  }
  __syncthreads();
  for (int job = wv; job < 16; job += 4) {
    int mt = job / 8, nt = job - mt * 8;
    int row = mt * 16 + (lane & 15);
    int ncol = nt * 16 + (lane & 15);
    int kb = q * 8;
    f32x4 acc = {0.f, 0.f, 0.f, 0.f};
    const u16* ap = &Y1[row * Y1P + kb];
    const u16* bp = &w2b[(size_t)ncol * 64 + kb];
#pragma unroll
    for (int ks = 0; ks < 2; ++ks) {
      short8 a = *(const short8*)(ap + ks * 32);
      short8 bb = *(const short8*)(bp + ks * 32);
      acc = __builtin_amdgcn_mfma_f32_16x16x32_bf16(a, bb, acc, 0, 0, 0);
    }
    float bias = b2v[ncol];
    int m0 = mt * 16 + q * 4;
#pragma unroll
    for (int r = 0; r < 4; ++r) {
      float v = fmaxf(acc[r] + bias, 0.0f);
      u16 bv = f2bf(v);
      h2out[(size_t)(bn0 + m0 + r) * 128 + ncol] = bv;
      Hb[(m0 + r) * HP + ncol] = bv;
    }
  }
  __syncthreads();
  for (int job = wv; job < 24; job += 4) {
    int mt = job / 12, nt = job - mt * 12;
    int row = mt * 16 + (lane & 15);
    int ncol = nt * 16 + (lane & 15);
    int kb = q * 8;
    f32x4 acc = {0.f, 0.f, 0.f, 0.f};
    const u16* ap = &Hb[row * HP + kb];
    const u16* bp = &wpq[(size_t)ncol * 128 + kb];
#pragma unroll
    for (int ks = 0; ks < 4; ++ks) {
      short8 a = *(const short8*)(ap + ks * 32);
      short8 bb = *(const short8*)(bp + ks * 32);
      acc = __builtin_amdgcn_mfma_f32_16x16x32_bf16(a, bb, acc, 0, 0, 0);
    }
    int m0 = mt * 16 + q * 4;
#pragma unroll
    for (int r = 0; r < 4; ++r)
      pq[(size_t)(bn0 + m0 + r) * 192 + ncol] = f2bf(acc[r]);
  }
}

// ---- fuse_pool v2: fused node3 (h2,m3 -> h3 in LDS) + fusion conv + max pool ----
// h1/h2/m3 bf16 -> all staging is pure copies
__global__ __launch_bounds__(256) void fuse_pool_mfma(
    const u16* __restrict__ h1, const u16* __restrict__ h2,
    const u16* __restrict__ m3, const u16* __restrict__ wn1b,
    const float* __restrict__ bn1v, const u16* __restrict__ wn2b,
    const float* __restrict__ bn2v, const u16* __restrict__ fwb,
    const float* __restrict__ fb, int* __restrict__ pooled) {
  constexpr int TP = 32;
  constexpr int XNP = 328;
  constexpr int Y1NP = 104;
  constexpr int XPB = 392;
  __shared__ __align__(16) char smem[TP * XPB * 2];
  u16* Xs = (u16*)smem;
  u16* Xn = (u16*)smem;
  __shared__ u16 Y1n[TP * Y1NP];
  __shared__ int pmax[512];
  const int tid = threadIdx.x;
  const int lane = tid & 63;
  const int wv = tid >> 6;
  const int q = lane >> 4;
  const int bn0 = blockIdx.x * TP;
  const int b = bn0 >> 10;
  for (int i = tid; i < 512; i += 256) pmax[i] = 0;
  // phase 0: Xn = [h2(128) | m3(192) | pad] - pure copies
  for (int i = tid; i < TP * 41; i += 256) {
    int p = i / 41, kc = i - p * 41;
    int k0 = kc * 8;
    if (kc < 16) {
      *(uint4*)&Xn[p * XNP + k0] =
          *(const uint4*)&h2[(size_t)(bn0 + p) * 128 + k0];
    } else if (kc < 40) {
      *(uint4*)&Xn[p * XNP + k0] =
          *(const uint4*)&m3[(size_t)(bn0 + p) * 192 + (k0 - 128)];
    } else {
      ushort8 z = {0, 0, 0, 0, 0, 0, 0, 0};
      *(ushort8*)&Xn[p * XNP + k0] = z;
    }
  }
  __syncthreads();
  for (int job = wv; job < 12; job += 4) {
    int mt = job / 6, nt = job - mt * 6;
    int row = mt * 16 + (lane & 15);
    int ncol = nt * 16 + (lane & 15);
    int kb = q * 8;
    f32x4 acc = {0.f, 0.f, 0.f, 0.f};
    const u16* ap = &Xn[row * XNP + kb];
    const u16* bp = &wn1b[(size_t)ncol * 320 + kb];
#pragma unroll
    for (int ks = 0; ks < 10; ++ks) {
      short8 a = *(const short8*)(ap + ks * 32);
      short8 bb = *(const short8*)(bp + ks * 32);
      acc = __builtin_amdgcn_mfma_f32_16x16x32_bf16(a, bb, acc, 0, 0, 0);
    }
    float bias = bn1v[ncol];
    int m0 = mt * 16 + q * 4;
#pragma unroll
    for (int r = 0; r < 4; ++r)
      Y1n[(m0 + r) * Y1NP + ncol] = f2bf(fmaxf(acc[r] + bias, 0.0f));
  }
  __syncthreads();
  // phase 2a: Xs cols 0..191 = [h1|h2] - pure copies
  for (int i = tid; i < TP * 24; i += 256) {
    int p = i / 24, kc = i - p * 24;
    int k0 = kc * 8;
    const u16* src = (k0 < 64) ? &h1[(size_t)(bn0 + p) * 64 + k0]
                               : &h2[(size_t)(bn0 + p) * 128 + (k0 - 64)];
    *(uint4*)&Xs[p * XPB + k0] = *(const uint4*)src;
  }
  if (tid < TP) {
    ushort8 z = {0, 0, 0, 0, 0, 0, 0, 0};
    *(ushort8*)&Xs[tid * XPB + 384] = z;
  }
  for (int job = wv; job < 24; job += 4) {
    int mt = job / 12, nt = job - mt * 12;
    int row = mt * 16 + (lane & 15);
    int ncol = nt * 16 + (lane & 15);
    int kb = q * 8;
    f32x4 acc = {0.f, 0.f, 0.f, 0.f};
    const u16* ap = &Y1n[row * Y1NP + kb];
    const u16* bp = &wn2b[(size_t)ncol * 96 + kb];
#pragma unroll
    for (int ks = 0; ks < 3; ++ks) {
      short8 a = *(const short8*)(ap + ks * 32);
      short8 bb = *(const short8*)(bp + ks * 32);
      acc = __builtin_amdgcn_mfma_f32_16x16x32_bf16(a, bb, acc, 0, 0, 0);
    }
    float bias = bn2v[ncol];
    int m0 = mt * 16 + q * 4;
#pragma unroll
    for (int r = 0; r < 4; ++r)
      Xs[(m0 + r) * XPB + 192 + ncol] = f2bf(fmaxf(acc[r] + bias, 0.0f));
  }
  __syncthreads();
  for (int job = wv; job < 64; job += 4) {
    int mt = job / 32, nt = job - mt * 32;
    int row = mt * 16 + (lane & 15);
    int ncol = nt * 16 + (lane & 15);
    int kb = q * 8;
    f32x4 acc = {0.f, 0.f, 0.f, 0.f};
    const u16* ap = &Xs[row * XPB + kb];
    const u16* bp = &fwb[(size_t)ncol * 384 + kb];
#pragma unroll
    for (int ks = 0; ks < 12; ++ks) {
      short8 a = *(const short8*)(ap + ks * 32);
      short8 bb = *(const short8*)(bp + ks * 32);
      acc = __builtin_amdgcn_mfma_f32_16x16x32_bf16(a, bb, acc, 0, 0, 0);
    }
    float bias = fb[ncol];
    float v = fmaxf(fmaxf(acc[0], acc[1]), fmaxf(acc[2], acc[3]));
    v = fmaxf(v + bias, 0.0f);
    v = fmaxf(v, __shfl_xor(v, 16));
    v = fmaxf(v, __shfl_xor(v, 32));
    if (lane < 16) atomicMax(&pmax[ncol], __float_as_int(v));
  }
  __syncthreads();
  for (int i = tid; i < 512; i += 256)
    atomicMax(&pooled[b * 512 + i], pmax[i]);
}

// ---------------- prediction head (blocks 0..7) + inputs echo copy (blocks 8+) ----------------
__global__ __launch_bounds__(256) void head_kernel(
    const int* __restrict__ pooledi, const float* __restrict__ p1w,
    const float* __restrict__ p1b, const float* __restrict__ p2w,
    const float* __restrict__ p2b, const float* __restrict__ p3w,
    const float* __restrict__ p3b, const float* __restrict__ inputs,
    float* __restrict__ out) {
  const int tid = threadIdx.x;
  if (blockIdx.x >= BDIM) {
    int idx = (blockIdx.x - BDIM) * 256 + tid;
    if (idx < (BDIM * 3 * NDIM) / 4) {
      const float4* src = (const float4*)inputs;
      float4* dst = (float4*)(out + BDIM * 40);
      dst[idx] = src[idx];
    }
    return;
  }
  __shared__ float xs[512], y1[256], y2[128];
  const int b = blockIdx.x;
  for (int i = tid; i < 512; i += 256) xs[i] = __int_as_float(pooledi[b * 512 + i]);
  __syncthreads();
  {
    float acc = p1b[tid];
    for (int c = 0; c < 512; ++c) acc += xs[c] * p1w[tid * 512 + c];
    y1[tid] = fmaxf(acc, 0.0f);
  }
  __syncthreads();
  if (tid < 128) {
    float acc = p2b[tid];
    for (int c = 0; c < 256; ++c) acc += y1[c] * p2w[tid * 256 + c];
    y2[tid] = fmaxf(acc, 0.0f);
  }
  __syncthreads();
  if (tid < 40) {
    float acc = p3b[tid];
    for (int c = 0; c < 128; ++c) acc += y2[c] * p3w[tid * 128 + c];
    out[b * 40 + tid] = acc;
  }
}

extern "C" void kernel_launch(void* const* d_in, const int* in_sizes, int n_in,
                              void* d_out, int out_size, void* d_ws,
                              size_t ws_size, hipStream_t stream) {
  const float* inputs = (const float*)d_in[0];
  const float* he_w1 = (const float*)d_in[1];
  const float* he_b1 = (const float*)d_in[2];
  const float* he_w2 = (const float*)d_in[3];
  const float* he_b2 = (const float*)d_in[4];
  const float* hn_w1 = (const float*)d_in[5];
  const float* hn_b1 = (const float*)d_in[6];
  const float* hn_w2 = (const float*)d_in[7];
  const float* hn_b2 = (const float*)d_in[8];
  const float* b1e_w1 = (const float*)d_in[9];
  const float* b1e_b1 = (const float*)d_in[10];
  const float* b1e_w2 = (const float*)d_in[11];
  const float* b1e_b2 = (const float*)d_in[12];
  const float* b1n_w1 = (const float*)d_in[13];
  const float* b1n_b1 = (const float*)d_in[14];
  const float* b1n_w2 = (const float*)d_in[15];
  const float* b1n_b2 = (const float*)d_in[16];
  const float* b2e_w1 = (const float*)d_in[17];
  const float* b2e_b1 = (const float*)d_in[18];
  const float* b2e_w2 = (const float*)d_in[19];
  const float* b2e_b2 = (const float*)d_in[20];
  const float* b2n_w1 = (const float*)d_in[21];
  const float* b2n_b1 = (const float*)d_in[22];
  const float* b2n_w2 = (const float*)d_in[23];
  const float* b2n_b2 = (const float*)d_in[24];
  const float* f_w = (const float*)d_in[25];
  const float* f_b = (const float*)d_in[26];
  const float* p1_w = (const float*)d_in[27];
  const float* p1_b = (const float*)d_in[28];
  const float* p2_w = (const float*)d_in[29];
  const float* p2_b = (const float*)d_in[30];
  const float* p3_w = (const float*)d_in[31];
  const float* p3_b = (const float*)d_in[32];
  float* out = (float*)d_out;

  char* ws = (char*)d_ws;
  size_t off = 0;
  auto alloc = [&](size_t bytes) {
    void* p = ws + off;
    off += (bytes + 255) & ~(size_t)255;
    return p;
  };
  int* nn = (int*)alloc((size_t)BDIM * NDIM * KNN * 4);
  float* m1 = (float*)alloc((size_t)BDIM * NDIM * 64 * 4);
  u16* h1 = (u16*)alloc((size_t)BDIM * NDIM * 64 * 2);         // bf16
  u16* e1 = (u16*)alloc((size_t)BDIM * NDIM * KNN * 64 * 2);   // bf16
  u16* m2 = (u16*)alloc((size_t)BDIM * NDIM * 128 * 2);        // bf16
  u16* h2 = (u16*)alloc((size_t)BDIM * NDIM * 128 * 2);        // bf16
  u16* e2 = (u16*)alloc((size_t)BDIM * NDIM * KNN * 128 * 2);  // bf16
  u16* m3 = (u16*)alloc((size_t)BDIM * NDIM * 192 * 2);        // bf16
  u16* pq2 = (u16*)alloc((size_t)BDIM * NDIM * 96 * 2);        // bf16
  u16* pq3 = (u16*)alloc((size_t)BDIM * NDIM * 192 * 2);       // bf16
  int* pooled = (int*)alloc((size_t)BDIM * 512 * 4);
  u16* w1b3e = (u16*)alloc((size_t)96 * 128 * 2);
  u16* wpq3 = (u16*)alloc((size_t)192 * 128 * 2);
  u16* w2b3 = (u16*)alloc((size_t)192 * 96 * 2);
  u16* w1b2e = (u16*)alloc((size_t)48 * 64 * 2);
  u16* wpq2 = (u16*)alloc((size_t)96 * 64 * 2);
  u16* w2b2 = (u16*)alloc((size_t)128 * 64 * 2);
  float* w1p1 = (float*)alloc((size_t)32 * 68 * 4);
  u16* fwb = (u16*)alloc((size_t)512 * 384 * 2);
  u16* w1b1 = (u16*)alloc((size_t)32 * 32 * 2);
  u16* w2b1 = (u16*)alloc((size_t)64 * 32 * 2);
  u16* wn1b = (u16*)alloc((size_t)96 * 320 * 2);
  u16* wn2b = (u16*)alloc((size_t)192 * 96 * 2);
  u16* wn21b = (u16*)alloc((size_t)48 * 192 * 2);
  u16* wn22b = (u16*)alloc((size_t)128 * 64 * 2);

  knn_wcvt<<<BDIM * 128 + 384, 512, 0, stream>>>(
      inputs, nn, b2e_w1, b2e_w2, b1e_w1, b1e_w2, hn_w1, f_w, he_w1, he_w2,
      b2n_w1, b2n_w2, b1n_w1, b1n_w2, w1b3e, wpq3, w2b3, w1b2e, wpq2, w2b2,
      w1p1, fwb, w1b1, w2b1, wn1b, wn2b, wn21b, wn22b, pooled);

  edge_mfma<4, 32, 32, 64, true, true><<<BDIM * NDIM / 4, 256, 0, stream>>>(
      nullptr, inputs, nn, w1b1, he_b1, w2b1, he_b2, nullptr, e1, (void*)m1);
  node_conv<64, 3, 64, 68, 32, 64, 96, true><<<BDIM * NDIM / 64, 256, 0, stream>>>(
      nullptr, inputs, m1, w1p1, hn_b1, hn_w2, hn_b2, h1, wpq2, pq2);

  edge_mfma<4, 64, 48, 128, true, false><<<BDIM * NDIM / 4, 256, 0, stream>>>(
      e1, nullptr, nn, w1b2e, b1e_b1, w2b2, b1e_b2, pq2, e2, (void*)m2);
  node2_mfma<<<BDIM * NDIM / 32, 256, 0, stream>>>(
      h1, m2, wn21b, b1n_b1, wn22b, b1n_b2, h2, wpq3, pq3);

  edge_mfma<4, 128, 96, 192, false, false><<<BDIM * NDIM / 4, 256, 0, stream>>>(
      e2, nullptr, nn, w1b3e, b2e_b1, w2b3, b2e_b2, pq3, nullptr, (void*)m3);

  fuse_pool_mfma<<<BDIM * NDIM / 32, 256, 0, stream>>>(
      h1, h2, m3, wn1b, b2n_b1, wn2b, b2n_b2, fwb, f_b, pooled);
  head_kernel<<<BDIM + 24, 256, 0, stream>>>(pooled, p1_w, p1_b, p2_w, p2_b,
                                             p3_w, p3_b, inputs, out);
}